// Round 6
// baseline (1356.647 us; speedup 1.0000x reference)
//
#include <hip/hip_runtime.h>
#include <hip/hip_bf16.h>

__device__ inline float gelu_f(float x) {
    return 0.5f * x * (1.0f + erff(x * 0.70710678118654752f));
}

__device__ inline float wave_sum(float v) {
#pragma unroll
    for (int o = 32; o > 0; o >>= 1) v += __shfl_xor(v, o);
    return v;
}
__device__ inline float wave_max(float v) {
#pragma unroll
    for (int o = 32; o > 0; o >>= 1) v = fmaxf(v, __shfl_xor(v, o));
    return v;
}

// ---------------- embedding + positional encoding ----------------
__global__ void embed_k(const int* __restrict__ tokens, const float* __restrict__ emb,
                        float* __restrict__ x) {
    int n = blockIdx.x, t = threadIdx.x;
    float e = emb[(size_t)tokens[n] * 256 + t];
    int k = t >> 1;
    float div = expf((float)(2 * k) * (-9.210340371976184f / 256.0f));
    float arg = (float)n * div;
    x[(size_t)n * 256 + t] = e + ((t & 1) ? cosf(arg) : sinf(arg));
}

// ---------------- tiled GEMM: C[m,n] = act(A[m,:K] . W[woff + n*ldw + koff + :K] + B[boff+n]) ----------------
template <int ACT>
__global__ __launch_bounds__(256) void gemm_bt(const float* __restrict__ A,
                                               const float* __restrict__ W,
                                               const float* __restrict__ bias,
                                               float* __restrict__ C,
                                               int M, int Nn, int K, int ldw, int koff,
                                               size_t woff, size_t boff) {
    __shared__ float As[32][68];
    __shared__ float Bs[32][68];
    const int tid = threadIdx.x;
    const int tx = tid & 15, ty = tid >> 4;
    const int bm = blockIdx.y * 64, bn = blockIdx.x * 64;
    float acc[4][4] = {};
    const int r = tid >> 2, c0 = (tid & 3) * 8;
    for (int k0 = 0; k0 < K; k0 += 32) {
        const float* asrc = A + (size_t)(bm + r) * K + k0 + c0;
        const float* wsrc = W + woff + (size_t)(bn + r) * ldw + koff + k0 + c0;
        float4 a0 = *(const float4*)asrc;
        float4 a1 = *(const float4*)(asrc + 4);
        float4 w0 = *(const float4*)wsrc;
        float4 w1 = *(const float4*)(wsrc + 4);
        As[c0 + 0][r] = a0.x; As[c0 + 1][r] = a0.y; As[c0 + 2][r] = a0.z; As[c0 + 3][r] = a0.w;
        As[c0 + 4][r] = a1.x; As[c0 + 5][r] = a1.y; As[c0 + 6][r] = a1.z; As[c0 + 7][r] = a1.w;
        Bs[c0 + 0][r] = w0.x; Bs[c0 + 1][r] = w0.y; Bs[c0 + 2][r] = w0.z; Bs[c0 + 3][r] = w0.w;
        Bs[c0 + 4][r] = w1.x; Bs[c0 + 5][r] = w1.y; Bs[c0 + 6][r] = w1.z; Bs[c0 + 7][r] = w1.w;
        __syncthreads();
#pragma unroll
        for (int kk = 0; kk < 32; ++kk) {
            float4 av = *(const float4*)&As[kk][ty * 4];
            float4 bv = *(const float4*)&Bs[kk][tx * 4];
            float a[4] = {av.x, av.y, av.z, av.w};
            float b[4] = {bv.x, bv.y, bv.z, bv.w};
#pragma unroll
            for (int i2 = 0; i2 < 4; ++i2)
#pragma unroll
                for (int j2 = 0; j2 < 4; ++j2)
                    acc[i2][j2] = fmaf(a[i2], b[j2], acc[i2][j2]);
        }
        __syncthreads();
    }
#pragma unroll
    for (int j2 = 0; j2 < 4; ++j2) {
        int n = bn + tx * 4 + j2;
        float bv = bias ? bias[boff + n] : 0.0f;
#pragma unroll
        for (int i2 = 0; i2 < 4; ++i2) {
            float v = acc[i2][j2] + bv;
            if (ACT == 1) v = fmaxf(v, 0.0f);
            if (ACT == 2) v = gelu_f(v);
            C[(size_t)(bm + ty * 4 + i2) * Nn + n] = v;
        }
    }
}

// ---------------- attention: wave per (head, query) ----------------
__global__ __launch_bounds__(256) void attn_k(const float* __restrict__ qkv,
                                              float* __restrict__ o) {
    __shared__ float sc[4][512];
    int t = threadIdx.x;
    int w = t >> 6, lane = t & 63;
    int q = blockIdx.x * 4 + w;
    int h = blockIdx.y;
    const float* qptr = qkv + (size_t)q * 768 + h * 32;
    const float* kbase = qkv + 256 + h * 32;
    const float* vbase = qkv + 512 + h * 32;
    float qv[32];
#pragma unroll
    for (int d = 0; d < 32; d += 4) {
        float4 f = *(const float4*)(qptr + d);
        qv[d] = f.x; qv[d + 1] = f.y; qv[d + 2] = f.z; qv[d + 3] = f.w;
    }
    float mx = -1e30f;
    for (int k = lane; k < 512; k += 64) {
        const float* kp = kbase + (size_t)k * 768;
        float s = 0.0f;
#pragma unroll
        for (int d = 0; d < 32; d += 4) {
            float4 f = *(const float4*)(kp + d);
            s = fmaf(qv[d], f.x, s); s = fmaf(qv[d + 1], f.y, s);
            s = fmaf(qv[d + 2], f.z, s); s = fmaf(qv[d + 3], f.w, s);
        }
        s *= 0.17677669529663687f;  // 1/sqrt(32)
        sc[w][k] = s;
        mx = fmaxf(mx, s);
    }
    mx = wave_max(mx);
    float sum = 0.0f;
    for (int k = lane; k < 512; k += 64) {
        float e = expf(sc[w][k] - mx);
        sc[w][k] = e;
        sum += e;
    }
    sum = wave_sum(sum);
    float inv = 1.0f / sum;
    __syncthreads();
    int d = lane & 31, half = lane >> 5;
    float accv = 0.0f;
    const float* vp = vbase + d;
    for (int k = half * 256; k < half * 256 + 256; ++k)
        accv = fmaf(sc[w][k], vp[(size_t)k * 768], accv);
    accv += __shfl_down(accv, 32);
    if (lane < 32) o[(size_t)q * 256 + h * 32 + d] = accv * inv;
}

// ---------------- residual + LayerNorm ----------------
__global__ void ln_res_k(float* __restrict__ x, const float* __restrict__ y,
                         const float* __restrict__ g, const float* __restrict__ b,
                         size_t goff) {
    int row = blockIdx.x, t = threadIdx.x;
    __shared__ float red[8];
    float v = x[row * 256 + t] + y[row * 256 + t];
    float s = wave_sum(v);
    if ((t & 63) == 0) red[t >> 6] = s;
    __syncthreads();
    float mean = (red[0] + red[1] + red[2] + red[3]) * (1.0f / 256.0f);
    float d = v - mean;
    float s2 = wave_sum(d * d);
    if ((t & 63) == 0) red[4 + (t >> 6)] = s2;
    __syncthreads();
    float var = (red[4] + red[5] + red[6] + red[7]) * (1.0f / 256.0f);
    x[row * 256 + t] = d * rsqrtf(var + 1e-5f) * g[goff + t] + b[goff + t];
}

// ---------------- alpha head ----------------
__global__ void alpha_k(const float* __restrict__ t1, const float* __restrict__ aW2,
                        const float* __restrict__ ab2, float* __restrict__ alphaf,
                        float* __restrict__ out_alpha) {
    int t = threadIdx.x, w = t >> 6, lane = t & 63;
    int n = blockIdx.x * 4 + w;
    const float* r = t1 + (size_t)n * 256;
    float s = 0.0f;
    for (int d = lane; d < 256; d += 64) s = fmaf(r[d], aW2[d], s);
    s = wave_sum(s);
    if (lane == 0) {
        float z = s + ab2[0];
        float a = 1.0f / (1.0f + expf(-z));
        float al = 1.2f + 2.3f * a;
        alphaf[n] = al;
        out_alpha[n] = al;
    }
}

// ---------------- CSOC kernel attention ----------------
__global__ void csock_k(const float* __restrict__ x, const float* __restrict__ alphaf,
                        float* __restrict__ latent, float* __restrict__ out_latent) {
    int i = blockIdx.x, t = threadIdx.x;
    __shared__ float wgt[512];
    __shared__ float red[4];
    float ai = alphaf[i];
    float lsum = 0.0f;
    for (int j = t; j < 512; j += 256) {
        float r = fabsf((float)(i - j)) + 1e-4f;
        float ap = 0.5f * (ai + alphaf[j]);
        float wv = powf(r, -ap) * expf(-r * 0.1f);
        wgt[j] = wv;
        lsum += wv;
    }
    float s = wave_sum(lsum);
    if ((t & 63) == 0) red[t >> 6] = s;
    __syncthreads();
    float S = red[0] + red[1] + red[2] + red[3] + 1e-8f;
    float acc = 0.0f;
    for (int j = 0; j < 512; ++j) acc = fmaf(wgt[j], x[(size_t)j * 256 + t], acc);
    float res = acc / S;
    latent[(size_t)i * 256 + t] = res;
    out_latent[(size_t)i * 256 + t] = res;
}

// ---------------- contact head ----------------
__global__ void contact_k(const float* __restrict__ h, float* __restrict__ out) {
    int i = blockIdx.x, t = threadIdx.x;
    __shared__ float hi[256];
    hi[t] = h[(size_t)i * 256 + t];
    __syncthreads();
    for (int j = t; j < 512; j += 256) {
        const float* hj = h + (size_t)j * 256;
        float s = 0.0f;
#pragma unroll 4
        for (int d = 0; d < 256; d += 4) {
            float4 a = *(const float4*)&hi[d];
            float4 b = *(const float4*)&hj[d];
            s = fmaf(a.x, b.x, s); s = fmaf(a.y, b.y, s);
            s = fmaf(a.z, b.z, s); s = fmaf(a.w, b.w, s);
        }
        out[(size_t)i * 512 + j] = 1.0f / (1.0f + expf(-s));
    }
}

// ---------------- distogram (separable first linear): out[i,j,b] = sum_d gelu(U[i,d]+V[j,d])*dW2[b,d] + db2[b] ----------------
__global__ __launch_bounds__(256) void disto_k(const float* __restrict__ U,
                                               const float* __restrict__ V,
                                               const float* __restrict__ dW2,
                                               const float* __restrict__ db2,
                                               float* __restrict__ out) {
    __shared__ float hs[16][260];
    __shared__ float Ui[256];
    int t = threadIdx.x;
    int i = blockIdx.x;
    const int b = t >> 2, qd = t & 3;
    float wreg[64];
#pragma unroll
    for (int q = 0; q < 64; ++q) wreg[q] = dW2[(size_t)b * 256 + qd * 64 + q];
    float breg = db2[b];
    Ui[t] = U[(size_t)i * 256 + t];
    __syncthreads();
    for (int j0 = 0; j0 < 512; j0 += 16) {
#pragma unroll
        for (int jj = 0; jj < 16; ++jj)
            hs[jj][t] = gelu_f(Ui[t] + V[(size_t)(j0 + jj) * 256 + t]);
        __syncthreads();
#pragma unroll
        for (int jj = 0; jj < 16; ++jj) {
            const float* hrow = &hs[jj][qd * 64];
            float s = 0.0f;
#pragma unroll
            for (int q = 0; q < 64; q += 4) {
                float4 h4 = *(const float4*)&hrow[q];
                s = fmaf(h4.x, wreg[q], s);
                s = fmaf(h4.y, wreg[q + 1], s);
                s = fmaf(h4.z, wreg[q + 2], s);
                s = fmaf(h4.w, wreg[q + 3], s);
            }
            s += __shfl_xor(s, 1);
            s += __shfl_xor(s, 2);
            if (qd == (jj & 3))
                out[((size_t)i * 512 + j0 + jj) * 64 + b] = s + breg;
        }
        __syncthreads();
    }
}

// ---------------- torsion head ----------------
__global__ void torsion_k(const float* __restrict__ t1, const float* __restrict__ tW2,
                          const float* __restrict__ tb2, float* __restrict__ phi,
                          float* __restrict__ psi) {
    int t = threadIdx.x, w = t >> 6, lane = t & 63;
    int n = blockIdx.x * 4 + w;
    const float* r = t1 + (size_t)n * 256;
    float s0 = 0.0f, s1 = 0.0f;
    for (int d = lane; d < 256; d += 64) {
        float v = r[d];
        s0 = fmaf(v, tW2[d], s0);
        s1 = fmaf(v, tW2[256 + d], s1);
    }
    s0 = wave_sum(s0);
    s1 = wave_sum(s1);
    if (lane == 0) {
        phi[n] = tanhf(s0 + tb2[0]) * 3.14159265358979323846f;
        psi[n] = tanhf(s1 + tb2[1]) * 3.14159265358979323846f;
    }
}

// ---------------- diffusion coordinate init ----------------
__global__ void diff_k(const float* __restrict__ latent, const float* __restrict__ pW,
                       const float* __restrict__ pb, const float* __restrict__ noise,
                       float* __restrict__ outc) {
    int idx = blockIdx.x * 256 + threadIdx.x;
    if (idx >= 512 * 3) return;
    int n = idx / 3, a = idx % 3;
    const float* r = latent + (size_t)n * 256;
    float s = pb[a];
    for (int d = 0; d < 256; ++d) s = fmaf(r[d], pW[(size_t)a * 256 + d], s);
    float c = noise[idx];
#pragma unroll
    for (int st = 9; st >= 0; --st) {
        float at = (float)(st + 1) * 0.1f;
        c = at * c + (1.0f - at) * s;
    }
    outc[idx] = c;
}

extern "C" void kernel_launch(void* const* d_in, const int* in_sizes, int n_in,
                              void* d_out, int out_size, void* d_ws, size_t ws_size,
                              hipStream_t stream) {
    const int* tokens  = (const int*)d_in[0];
    const float* noise = (const float*)d_in[1];
    const float* emb   = (const float*)d_in[2];
    const float* Wqkv  = (const float*)d_in[3];
    const float* bqkv  = (const float*)d_in[4];
    const float* Wo    = (const float*)d_in[5];
    const float* bo    = (const float*)d_in[6];
    const float* ln1_g = (const float*)d_in[7];
    const float* ln1_b = (const float*)d_in[8];
    const float* W1    = (const float*)d_in[9];
    const float* b1    = (const float*)d_in[10];
    const float* W2    = (const float*)d_in[11];
    const float* b2    = (const float*)d_in[12];
    const float* ln2_g = (const float*)d_in[13];
    const float* ln2_b = (const float*)d_in[14];
    const float* aW1   = (const float*)d_in[15];
    const float* ab1   = (const float*)d_in[16];
    const float* aW2   = (const float*)d_in[17];
    const float* ab2   = (const float*)d_in[18];
    const float* cW    = (const float*)d_in[19];
    const float* cb    = (const float*)d_in[20];
    const float* dW1   = (const float*)d_in[21];
    const float* db1   = (const float*)d_in[22];
    const float* dW2   = (const float*)d_in[23];
    const float* db2   = (const float*)d_in[24];
    const float* tW1   = (const float*)d_in[25];
    const float* tb1   = (const float*)d_in[26];
    const float* tW2   = (const float*)d_in[27];
    const float* tb2   = (const float*)d_in[28];
    const float* pW    = (const float*)d_in[29];
    const float* pb    = (const float*)d_in[30];

    // output layout (FLOAT32, concatenated in return order)
    float* out         = (float*)d_out;
    float* out_latent  = out;               // 131072
    float* out_alpha   = out + 131072;      // 512
    float* out_contact = out + 131584;      // 262144
    float* out_disto   = out + 393728;      // 16777216
    float* out_phi     = out + 17170944;    // 512
    float* out_psi     = out + 17171456;    // 512
    float* out_c       = out + 17171968;    // 1536

    // transient scratch inside out_disto (67 MB as f32); disto_k runs LAST and
    // reads only U/V/latent (d_ws) + weights while overwriting this region.
    float* scratch = out_disto;
    float* x    = scratch;            // 131072
    float* qkv  = scratch + 131072;   // 393216
    float* o    = scratch + 524288;   // 131072
    float* ffh  = scratch + 655360;   // 524288
    float* y    = scratch + 1179648;  // 131072
    float* hbuf = scratch + 1310720;  // 131072
    float* t1   = scratch + 1441792;  // 131072  (ends 1572864 << 16777216)

    // persistent across disto_k: keep in d_ws (1.54 MB)
    float* latentf = (float*)d_ws;      // 131072
    float* U       = latentf + 131072;  // 131072
    float* Vv      = U + 131072;        // 131072
    float* alphaf  = Vv + 131072;       // 512

    embed_k<<<512, 256, 0, stream>>>(tokens, emb, x);

    for (int l = 0; l < 4; ++l) {
        gemm_bt<0><<<dim3(12, 8), 256, 0, stream>>>(x, Wqkv, bqkv, qkv,
                                                    512, 768, 256, 256, 0,
                                                    (size_t)l * 196608, (size_t)l * 768);
        attn_k<<<dim3(128, 8), 256, 0, stream>>>(qkv, o);
        gemm_bt<0><<<dim3(4, 8), 256, 0, stream>>>(o, Wo, bo, y,
                                                   512, 256, 256, 256, 0,
                                                   (size_t)l * 65536, (size_t)l * 256);
        ln_res_k<<<512, 256, 0, stream>>>(x, y, ln1_g, ln1_b, (size_t)l * 256);
        gemm_bt<1><<<dim3(16, 8), 256, 0, stream>>>(x, W1, b1, ffh,
                                                    512, 1024, 256, 256, 0,
                                                    (size_t)l * 262144, (size_t)l * 1024);
        gemm_bt<0><<<dim3(4, 8), 256, 0, stream>>>(ffh, W2, b2, y,
                                                   512, 256, 1024, 1024, 0,
                                                   (size_t)l * 262144, (size_t)l * 256);
        ln_res_k<<<512, 256, 0, stream>>>(x, y, ln2_g, ln2_b, (size_t)l * 256);
    }

    // alpha head
    gemm_bt<2><<<dim3(4, 8), 256, 0, stream>>>(x, aW1, ab1, t1,
                                               512, 256, 256, 256, 0, 0, 0);
    alpha_k<<<128, 256, 0, stream>>>(t1, aW2, ab2, alphaf, out_alpha);

    // CSOC kernel attention -> latent
    csock_k<<<512, 256, 0, stream>>>(x, alphaf, latentf, out_latent);

    // contact head
    gemm_bt<0><<<dim3(4, 8), 256, 0, stream>>>(latentf, cW, cb, hbuf,
                                               512, 256, 256, 256, 0, 0, 0);
    contact_k<<<512, 256, 0, stream>>>(hbuf, out_contact);

    // distogram first linear (separable): U = latent.dW1[:,:256]^T + db1 ; V = latent.dW1[:,256:]^T
    gemm_bt<0><<<dim3(4, 8), 256, 0, stream>>>(latentf, dW1, db1, U,
                                               512, 256, 256, 512, 0, 0, 0);
    gemm_bt<0><<<dim3(4, 8), 256, 0, stream>>>(latentf, dW1, nullptr, Vv,
                                               512, 256, 256, 512, 256, 0, 0);

    // torsion head (uses t1 scratch -> before disto_k)
    gemm_bt<2><<<dim3(4, 8), 256, 0, stream>>>(latentf, tW1, tb1, t1,
                                               512, 256, 256, 256, 0, 0, 0);
    torsion_k<<<128, 256, 0, stream>>>(t1, tW2, tb2, out_phi, out_psi);

    // diffusion coordinate init
    diff_k<<<6, 256, 0, stream>>>(latentf, pW, pb, noise, out_c);

    // distogram LAST: overwrites the scratch region with the real output
    disto_k<<<512, 256, 0, stream>>>(U, Vv, dW2, db2, out_disto);
}

// Round 7
// 934.207 us; speedup vs baseline: 1.4522x; 1.4522x over previous
//
#include <hip/hip_runtime.h>
#include <hip/hip_bf16.h>

__device__ inline float gelu_f(float x) {
    return 0.5f * x * (1.0f + erff(x * 0.70710678118654752f));
}

__device__ inline float wave_sum(float v) {
#pragma unroll
    for (int o = 32; o > 0; o >>= 1) v += __shfl_xor(v, o);
    return v;
}
__device__ inline float wave_max(float v) {
#pragma unroll
    for (int o = 32; o > 0; o >>= 1) v = fmaxf(v, __shfl_xor(v, o));
    return v;
}

// ---------------- embedding + positional encoding ----------------
__global__ void embed_k(const int* __restrict__ tokens, const float* __restrict__ emb,
                        float* __restrict__ x) {
    int n = blockIdx.x, t = threadIdx.x;
    float e = emb[(size_t)tokens[n] * 256 + t];
    int k = t >> 1;
    float div = expf((float)(2 * k) * (-9.210340371976184f / 256.0f));
    float arg = (float)n * div;
    x[(size_t)n * 256 + t] = e + ((t & 1) ? cosf(arg) : sinf(arg));
}

// ---------------- tiled GEMM: C[m,n] = act(A[m,:K] . W[woff + n*ldw + koff + :K] + B[boff+n]) ----------------
template <int ACT>
__global__ __launch_bounds__(256) void gemm_bt(const float* __restrict__ A,
                                               const float* __restrict__ W,
                                               const float* __restrict__ bias,
                                               float* __restrict__ C,
                                               int M, int Nn, int K, int ldw, int koff,
                                               size_t woff, size_t boff) {
    __shared__ float As[32][68];
    __shared__ float Bs[32][68];
    const int tid = threadIdx.x;
    const int tx = tid & 15, ty = tid >> 4;
    const int bm = blockIdx.y * 64, bn = blockIdx.x * 64;
    float acc[4][4] = {};
    const int r = tid >> 2, c0 = (tid & 3) * 8;
    for (int k0 = 0; k0 < K; k0 += 32) {
        const float* asrc = A + (size_t)(bm + r) * K + k0 + c0;
        const float* wsrc = W + woff + (size_t)(bn + r) * ldw + koff + k0 + c0;
        float4 a0 = *(const float4*)asrc;
        float4 a1 = *(const float4*)(asrc + 4);
        float4 w0 = *(const float4*)wsrc;
        float4 w1 = *(const float4*)(wsrc + 4);
        As[c0 + 0][r] = a0.x; As[c0 + 1][r] = a0.y; As[c0 + 2][r] = a0.z; As[c0 + 3][r] = a0.w;
        As[c0 + 4][r] = a1.x; As[c0 + 5][r] = a1.y; As[c0 + 6][r] = a1.z; As[c0 + 7][r] = a1.w;
        Bs[c0 + 0][r] = w0.x; Bs[c0 + 1][r] = w0.y; Bs[c0 + 2][r] = w0.z; Bs[c0 + 3][r] = w0.w;
        Bs[c0 + 4][r] = w1.x; Bs[c0 + 5][r] = w1.y; Bs[c0 + 6][r] = w1.z; Bs[c0 + 7][r] = w1.w;
        __syncthreads();
#pragma unroll
        for (int kk = 0; kk < 32; ++kk) {
            float4 av = *(const float4*)&As[kk][ty * 4];
            float4 bv = *(const float4*)&Bs[kk][tx * 4];
            float a[4] = {av.x, av.y, av.z, av.w};
            float b[4] = {bv.x, bv.y, bv.z, bv.w};
#pragma unroll
            for (int i2 = 0; i2 < 4; ++i2)
#pragma unroll
                for (int j2 = 0; j2 < 4; ++j2)
                    acc[i2][j2] = fmaf(a[i2], b[j2], acc[i2][j2]);
        }
        __syncthreads();
    }
#pragma unroll
    for (int j2 = 0; j2 < 4; ++j2) {
        int n = bn + tx * 4 + j2;
        float bv = bias ? bias[boff + n] : 0.0f;
#pragma unroll
        for (int i2 = 0; i2 < 4; ++i2) {
            float v = acc[i2][j2] + bv;
            if (ACT == 1) v = fmaxf(v, 0.0f);
            if (ACT == 2) v = gelu_f(v);
            C[(size_t)(bm + ty * 4 + i2) * Nn + n] = v;
        }
    }
}

// ---------------- attention: wave per (head, query) ----------------
__global__ __launch_bounds__(256) void attn_k(const float* __restrict__ qkv,
                                              float* __restrict__ o) {
    __shared__ float sc[4][512];
    int t = threadIdx.x;
    int w = t >> 6, lane = t & 63;
    int q = blockIdx.x * 4 + w;
    int h = blockIdx.y;
    const float* qptr = qkv + (size_t)q * 768 + h * 32;
    const float* kbase = qkv + 256 + h * 32;
    const float* vbase = qkv + 512 + h * 32;
    float qv[32];
#pragma unroll
    for (int d = 0; d < 32; d += 4) {
        float4 f = *(const float4*)(qptr + d);
        qv[d] = f.x; qv[d + 1] = f.y; qv[d + 2] = f.z; qv[d + 3] = f.w;
    }
    float mx = -1e30f;
    for (int k = lane; k < 512; k += 64) {
        const float* kp = kbase + (size_t)k * 768;
        float s = 0.0f;
#pragma unroll
        for (int d = 0; d < 32; d += 4) {
            float4 f = *(const float4*)(kp + d);
            s = fmaf(qv[d], f.x, s); s = fmaf(qv[d + 1], f.y, s);
            s = fmaf(qv[d + 2], f.z, s); s = fmaf(qv[d + 3], f.w, s);
        }
        s *= 0.17677669529663687f;  // 1/sqrt(32)
        sc[w][k] = s;
        mx = fmaxf(mx, s);
    }
    mx = wave_max(mx);
    float sum = 0.0f;
    for (int k = lane; k < 512; k += 64) {
        float e = expf(sc[w][k] - mx);
        sc[w][k] = e;
        sum += e;
    }
    sum = wave_sum(sum);
    float inv = 1.0f / sum;
    __syncthreads();
    int d = lane & 31, half = lane >> 5;
    float accv = 0.0f;
    const float* vp = vbase + d;
    for (int k = half * 256; k < half * 256 + 256; ++k)
        accv = fmaf(sc[w][k], vp[(size_t)k * 768], accv);
    accv += __shfl_down(accv, 32);
    if (lane < 32) o[(size_t)q * 256 + h * 32 + d] = accv * inv;
}

// ---------------- residual + LayerNorm ----------------
__global__ void ln_res_k(float* __restrict__ x, const float* __restrict__ y,
                         const float* __restrict__ g, const float* __restrict__ b,
                         size_t goff) {
    int row = blockIdx.x, t = threadIdx.x;
    __shared__ float red[8];
    float v = x[row * 256 + t] + y[row * 256 + t];
    float s = wave_sum(v);
    if ((t & 63) == 0) red[t >> 6] = s;
    __syncthreads();
    float mean = (red[0] + red[1] + red[2] + red[3]) * (1.0f / 256.0f);
    float d = v - mean;
    float s2 = wave_sum(d * d);
    if ((t & 63) == 0) red[4 + (t >> 6)] = s2;
    __syncthreads();
    float var = (red[4] + red[5] + red[6] + red[7]) * (1.0f / 256.0f);
    x[row * 256 + t] = d * rsqrtf(var + 1e-5f) * g[goff + t] + b[goff + t];
}

// ---------------- alpha head ----------------
__global__ void alpha_k(const float* __restrict__ t1, const float* __restrict__ aW2,
                        const float* __restrict__ ab2, float* __restrict__ alphaf,
                        float* __restrict__ out_alpha) {
    int t = threadIdx.x, w = t >> 6, lane = t & 63;
    int n = blockIdx.x * 4 + w;
    const float* r = t1 + (size_t)n * 256;
    float s = 0.0f;
    for (int d = lane; d < 256; d += 64) s = fmaf(r[d], aW2[d], s);
    s = wave_sum(s);
    if (lane == 0) {
        float z = s + ab2[0];
        float a = 1.0f / (1.0f + expf(-z));
        float al = 1.2f + 2.3f * a;
        alphaf[n] = al;
        out_alpha[n] = al;
    }
}

// ---------------- CSOC kernel attention ----------------
__global__ void csock_k(const float* __restrict__ x, const float* __restrict__ alphaf,
                        float* __restrict__ latent, float* __restrict__ out_latent) {
    int i = blockIdx.x, t = threadIdx.x;
    __shared__ float wgt[512];
    __shared__ float red[4];
    float ai = alphaf[i];
    float lsum = 0.0f;
    for (int j = t; j < 512; j += 256) {
        float r = fabsf((float)(i - j)) + 1e-4f;
        float ap = 0.5f * (ai + alphaf[j]);
        float wv = powf(r, -ap) * expf(-r * 0.1f);
        wgt[j] = wv;
        lsum += wv;
    }
    float s = wave_sum(lsum);
    if ((t & 63) == 0) red[t >> 6] = s;
    __syncthreads();
    float S = red[0] + red[1] + red[2] + red[3] + 1e-8f;
    float acc = 0.0f;
    for (int j = 0; j < 512; ++j) acc = fmaf(wgt[j], x[(size_t)j * 256 + t], acc);
    float res = acc / S;
    latent[(size_t)i * 256 + t] = res;
    out_latent[(size_t)i * 256 + t] = res;
}

// ---------------- contact head ----------------
__global__ void contact_k(const float* __restrict__ h, float* __restrict__ out) {
    int i = blockIdx.x, t = threadIdx.x;
    __shared__ float hi[256];
    hi[t] = h[(size_t)i * 256 + t];
    __syncthreads();
    for (int j = t; j < 512; j += 256) {
        const float* hj = h + (size_t)j * 256;
        float s = 0.0f;
#pragma unroll 4
        for (int d = 0; d < 256; d += 4) {
            float4 a = *(const float4*)&hi[d];
            float4 b = *(const float4*)&hj[d];
            s = fmaf(a.x, b.x, s); s = fmaf(a.y, b.y, s);
            s = fmaf(a.z, b.z, s); s = fmaf(a.w, b.w, s);
        }
        out[(size_t)i * 512 + j] = 1.0f / (1.0f + expf(-s));
    }
}

// ---------------- distogram v2 ----------------
// out[i,j,b] = sum_d gelu(U[i,d]+V[j,d]) * dW2[b,d] + db2[b]
// grid (512, 4): block = one i, 128 j's. 256 threads: bin b = t>>2, K-quarter
// qd = t&3. Per-bin weight quarter lives in 16 float4 VGPRs, loaded through the
// same bank-rotation used on the LDS reads (col = (4q+8qd)&63), so the 4
// concurrent quarter-reads hit disjoint bank groups {q,q+8,q+16,q+24} mod 32.
// __launch_bounds__(256,4) caps at 128 VGPR so w16 stays in registers.
__global__ __launch_bounds__(256, 4) void disto_k(const float* __restrict__ U,
                                                  const float* __restrict__ V,
                                                  const float* __restrict__ dW2,
                                                  const float* __restrict__ db2,
                                                  float* __restrict__ out) {
    __shared__ float hs[16][260];
    __shared__ float Ui[256];
    const int t = threadIdx.x;
    const int i = blockIdx.x;
    const int jbase = blockIdx.y * 128;
    const int b = t >> 2, qd = t & 3;
    float4 w16[16];
#pragma unroll
    for (int q = 0; q < 16; ++q) {
        int col = ((q * 4 + 8 * qd) & 63);
        w16[q] = *(const float4*)&dW2[(size_t)b * 256 + qd * 64 + col];
    }
    const float breg = db2[b];
    Ui[t] = U[(size_t)i * 256 + t];
    __syncthreads();
    for (int g = 0; g < 8; ++g) {
        const int j0 = jbase + g * 16;
#pragma unroll
        for (int jj = 0; jj < 16; ++jj)
            hs[jj][t] = gelu_f(Ui[t] + V[(size_t)(j0 + jj) * 256 + t]);
        __syncthreads();
#pragma unroll
        for (int jj = 0; jj < 16; ++jj) {
            const float* hrow = &hs[jj][qd * 64];
            float s = 0.0f;
#pragma unroll
            for (int q = 0; q < 16; ++q) {
                int col = ((q * 4 + 8 * qd) & 63);
                float4 h4 = *(const float4*)&hrow[col];
                s = fmaf(h4.x, w16[q].x, s);
                s = fmaf(h4.y, w16[q].y, s);
                s = fmaf(h4.z, w16[q].z, s);
                s = fmaf(h4.w, w16[q].w, s);
            }
            s += __shfl_xor(s, 1);
            s += __shfl_xor(s, 2);
            if (qd == (jj & 3))
                out[((size_t)i * 512 + j0 + jj) * 64 + b] = s + breg;
        }
        __syncthreads();
    }
}

// ---------------- torsion head ----------------
__global__ void torsion_k(const float* __restrict__ t1, const float* __restrict__ tW2,
                          const float* __restrict__ tb2, float* __restrict__ phi,
                          float* __restrict__ psi) {
    int t = threadIdx.x, w = t >> 6, lane = t & 63;
    int n = blockIdx.x * 4 + w;
    const float* r = t1 + (size_t)n * 256;
    float s0 = 0.0f, s1 = 0.0f;
    for (int d = lane; d < 256; d += 64) {
        float v = r[d];
        s0 = fmaf(v, tW2[d], s0);
        s1 = fmaf(v, tW2[256 + d], s1);
    }
    s0 = wave_sum(s0);
    s1 = wave_sum(s1);
    if (lane == 0) {
        phi[n] = tanhf(s0 + tb2[0]) * 3.14159265358979323846f;
        psi[n] = tanhf(s1 + tb2[1]) * 3.14159265358979323846f;
    }
}

// ---------------- diffusion coordinate init ----------------
__global__ void diff_k(const float* __restrict__ latent, const float* __restrict__ pW,
                       const float* __restrict__ pb, const float* __restrict__ noise,
                       float* __restrict__ outc) {
    int idx = blockIdx.x * 256 + threadIdx.x;
    if (idx >= 512 * 3) return;
    int n = idx / 3, a = idx % 3;
    const float* r = latent + (size_t)n * 256;
    float s = pb[a];
    for (int d = 0; d < 256; ++d) s = fmaf(r[d], pW[(size_t)a * 256 + d], s);
    float c = noise[idx];
#pragma unroll
    for (int st = 9; st >= 0; --st) {
        float at = (float)(st + 1) * 0.1f;
        c = at * c + (1.0f - at) * s;
    }
    outc[idx] = c;
}

extern "C" void kernel_launch(void* const* d_in, const int* in_sizes, int n_in,
                              void* d_out, int out_size, void* d_ws, size_t ws_size,
                              hipStream_t stream) {
    const int* tokens  = (const int*)d_in[0];
    const float* noise = (const float*)d_in[1];
    const float* emb   = (const float*)d_in[2];
    const float* Wqkv  = (const float*)d_in[3];
    const float* bqkv  = (const float*)d_in[4];
    const float* Wo    = (const float*)d_in[5];
    const float* bo    = (const float*)d_in[6];
    const float* ln1_g = (const float*)d_in[7];
    const float* ln1_b = (const float*)d_in[8];
    const float* W1    = (const float*)d_in[9];
    const float* b1    = (const float*)d_in[10];
    const float* W2    = (const float*)d_in[11];
    const float* b2    = (const float*)d_in[12];
    const float* ln2_g = (const float*)d_in[13];
    const float* ln2_b = (const float*)d_in[14];
    const float* aW1   = (const float*)d_in[15];
    const float* ab1   = (const float*)d_in[16];
    const float* aW2   = (const float*)d_in[17];
    const float* ab2   = (const float*)d_in[18];
    const float* cW    = (const float*)d_in[19];
    const float* cb    = (const float*)d_in[20];
    const float* dW1   = (const float*)d_in[21];
    const float* db1   = (const float*)d_in[22];
    const float* dW2   = (const float*)d_in[23];
    const float* db2   = (const float*)d_in[24];
    const float* tW1   = (const float*)d_in[25];
    const float* tb1   = (const float*)d_in[26];
    const float* tW2   = (const float*)d_in[27];
    const float* tb2   = (const float*)d_in[28];
    const float* pW    = (const float*)d_in[29];
    const float* pb    = (const float*)d_in[30];

    // output layout (FLOAT32, concatenated in return order)
    float* out         = (float*)d_out;
    float* out_latent  = out;               // 131072
    float* out_alpha   = out + 131072;      // 512
    float* out_contact = out + 131584;      // 262144
    float* out_disto   = out + 393728;      // 16777216
    float* out_phi     = out + 17170944;    // 512
    float* out_psi     = out + 17171456;    // 512
    float* out_c       = out + 17171968;    // 1536

    // transient scratch inside out_disto (67 MB as f32); disto_k runs LAST and
    // reads only U/V (d_ws) + weights while overwriting this region.
    float* scratch = out_disto;
    float* x    = scratch;            // 131072
    float* qkv  = scratch + 131072;   // 393216
    float* o    = scratch + 524288;   // 131072
    float* ffh  = scratch + 655360;   // 524288
    float* y    = scratch + 1179648;  // 131072
    float* hbuf = scratch + 1310720;  // 131072
    float* t1   = scratch + 1441792;  // 131072  (ends 1572864 << 16777216)

    // persistent across disto_k: keep in d_ws (1.54 MB)
    float* latentf = (float*)d_ws;      // 131072
    float* U       = latentf + 131072;  // 131072
    float* Vv      = U + 131072;        // 131072
    float* alphaf  = Vv + 131072;       // 512

    embed_k<<<512, 256, 0, stream>>>(tokens, emb, x);

    for (int l = 0; l < 4; ++l) {
        gemm_bt<0><<<dim3(12, 8), 256, 0, stream>>>(x, Wqkv, bqkv, qkv,
                                                    512, 768, 256, 256, 0,
                                                    (size_t)l * 196608, (size_t)l * 768);
        attn_k<<<dim3(128, 8), 256, 0, stream>>>(qkv, o);
        gemm_bt<0><<<dim3(4, 8), 256, 0, stream>>>(o, Wo, bo, y,
                                                   512, 256, 256, 256, 0,
                                                   (size_t)l * 65536, (size_t)l * 256);
        ln_res_k<<<512, 256, 0, stream>>>(x, y, ln1_g, ln1_b, (size_t)l * 256);
        gemm_bt<1><<<dim3(16, 8), 256, 0, stream>>>(x, W1, b1, ffh,
                                                    512, 1024, 256, 256, 0,
                                                    (size_t)l * 262144, (size_t)l * 1024);
        gemm_bt<0><<<dim3(4, 8), 256, 0, stream>>>(ffh, W2, b2, y,
                                                   512, 256, 1024, 1024, 0,
                                                   (size_t)l * 262144, (size_t)l * 256);
        ln_res_k<<<512, 256, 0, stream>>>(x, y, ln2_g, ln2_b, (size_t)l * 256);
    }

    // alpha head
    gemm_bt<2><<<dim3(4, 8), 256, 0, stream>>>(x, aW1, ab1, t1,
                                               512, 256, 256, 256, 0, 0, 0);
    alpha_k<<<128, 256, 0, stream>>>(t1, aW2, ab2, alphaf, out_alpha);

    // CSOC kernel attention -> latent
    csock_k<<<512, 256, 0, stream>>>(x, alphaf, latentf, out_latent);

    // contact head
    gemm_bt<0><<<dim3(4, 8), 256, 0, stream>>>(latentf, cW, cb, hbuf,
                                               512, 256, 256, 256, 0, 0, 0);
    contact_k<<<512, 256, 0, stream>>>(hbuf, out_contact);

    // distogram first linear (separable): U = latent.dW1[:,:256]^T + db1 ; V = latent.dW1[:,256:]^T
    gemm_bt<0><<<dim3(4, 8), 256, 0, stream>>>(latentf, dW1, db1, U,
                                               512, 256, 256, 512, 0, 0, 0);
    gemm_bt<0><<<dim3(4, 8), 256, 0, stream>>>(latentf, dW1, nullptr, Vv,
                                               512, 256, 256, 512, 256, 0, 0);

    // torsion head (uses t1 scratch -> before disto_k)
    gemm_bt<2><<<dim3(4, 8), 256, 0, stream>>>(latentf, tW1, tb1, t1,
                                               512, 256, 256, 256, 0, 0, 0);
    torsion_k<<<128, 256, 0, stream>>>(t1, tW2, tb2, out_phi, out_psi);

    // diffusion coordinate init
    diff_k<<<6, 256, 0, stream>>>(latentf, pW, pb, noise, out_c);

    // distogram LAST: overwrites the scratch region with the real output
    disto_k<<<dim3(512, 4), 256, 0, stream>>>(U, Vv, dW2, db2, out_disto);
}

// Round 8
// 722.239 us; speedup vs baseline: 1.8784x; 1.2935x over previous
//
#include <hip/hip_runtime.h>
#include <hip/hip_bf16.h>

typedef __attribute__((ext_vector_type(8))) short bf16x8;
typedef __attribute__((ext_vector_type(4))) float f32x4;

__device__ inline float gelu_f(float x) {
    return 0.5f * x * (1.0f + erff(x * 0.70710678118654752f));
}

__device__ inline unsigned short f2bfu(float x) {
    __hip_bfloat16 b = __float2bfloat16(x);
    return *reinterpret_cast<unsigned short*>(&b);
}

__device__ inline float wave_sum(float v) {
#pragma unroll
    for (int o = 32; o > 0; o >>= 1) v += __shfl_xor(v, o);
    return v;
}
__device__ inline float wave_max(float v) {
#pragma unroll
    for (int o = 32; o > 0; o >>= 1) v = fmaxf(v, __shfl_xor(v, o));
    return v;
}

// ---------------- embedding + positional encoding ----------------
__global__ void embed_k(const int* __restrict__ tokens, const float* __restrict__ emb,
                        float* __restrict__ x) {
    int n = blockIdx.x, t = threadIdx.x;
    float e = emb[(size_t)tokens[n] * 256 + t];
    int k = t >> 1;
    float div = expf((float)(2 * k) * (-9.210340371976184f / 256.0f));
    float arg = (float)n * div;
    x[(size_t)n * 256 + t] = e + ((t & 1) ? cosf(arg) : sinf(arg));
}

// ---------------- tiled GEMM 32x64: C[m,n] = act(A[m,:K].W[woff+n*ldw+koff+:K] + B[boff+n]) ----------------
template <int ACT>
__global__ __launch_bounds__(256) void gemm32(const float* __restrict__ A,
                                              const float* __restrict__ W,
                                              const float* __restrict__ bias,
                                              float* __restrict__ C,
                                              int M, int Nn, int K, int ldw, int koff,
                                              size_t woff, size_t boff) {
    __shared__ float As[32][34];
    __shared__ float Bs[32][68];
    const int tid = threadIdx.x;
    const int tx = tid & 15, ty = tid >> 4;
    const int bm = blockIdx.y * 32, bn = blockIdx.x * 64;
    float acc[2][4] = {};
    const int ra = tid >> 3, ca = (tid & 7) * 4;   // A stage: 32 rows x 32 k
    const int rw = tid >> 2, cw = (tid & 3) * 8;   // W stage: 64 rows x 32 k
    for (int k0 = 0; k0 < K; k0 += 32) {
        float4 a0 = *(const float4*)(A + (size_t)(bm + ra) * K + k0 + ca);
        const float* wsrc = W + woff + (size_t)(bn + rw) * ldw + koff + k0 + cw;
        float4 w0 = *(const float4*)wsrc;
        float4 w1 = *(const float4*)(wsrc + 4);
        As[ca + 0][ra] = a0.x; As[ca + 1][ra] = a0.y; As[ca + 2][ra] = a0.z; As[ca + 3][ra] = a0.w;
        Bs[cw + 0][rw] = w0.x; Bs[cw + 1][rw] = w0.y; Bs[cw + 2][rw] = w0.z; Bs[cw + 3][rw] = w0.w;
        Bs[cw + 4][rw] = w1.x; Bs[cw + 5][rw] = w1.y; Bs[cw + 6][rw] = w1.z; Bs[cw + 7][rw] = w1.w;
        __syncthreads();
#pragma unroll
        for (int kk = 0; kk < 32; ++kk) {
            float a0s = As[kk][ty * 2];
            float a1s = As[kk][ty * 2 + 1];
            float4 bv = *(const float4*)&Bs[kk][tx * 4];
            acc[0][0] = fmaf(a0s, bv.x, acc[0][0]); acc[0][1] = fmaf(a0s, bv.y, acc[0][1]);
            acc[0][2] = fmaf(a0s, bv.z, acc[0][2]); acc[0][3] = fmaf(a0s, bv.w, acc[0][3]);
            acc[1][0] = fmaf(a1s, bv.x, acc[1][0]); acc[1][1] = fmaf(a1s, bv.y, acc[1][1]);
            acc[1][2] = fmaf(a1s, bv.z, acc[1][2]); acc[1][3] = fmaf(a1s, bv.w, acc[1][3]);
        }
        __syncthreads();
    }
#pragma unroll
    for (int j2 = 0; j2 < 4; ++j2) {
        int n = bn + tx * 4 + j2;
        float bv = bias ? bias[boff + n] : 0.0f;
#pragma unroll
        for (int i2 = 0; i2 < 2; ++i2) {
            float v = acc[i2][j2] + bv;
            if (ACT == 1) v = fmaxf(v, 0.0f);
            if (ACT == 2) v = gelu_f(v);
            C[(size_t)(bm + ty * 2 + i2) * Nn + n] = v;
        }
    }
}

// ---------------- attention: wave per (head, query) ----------------
__global__ __launch_bounds__(256) void attn_k(const float* __restrict__ qkv,
                                              float* __restrict__ o) {
    __shared__ float sc[4][512];
    int t = threadIdx.x;
    int w = t >> 6, lane = t & 63;
    int q = blockIdx.x * 4 + w;
    int h = blockIdx.y;
    const float* qptr = qkv + (size_t)q * 768 + h * 32;
    const float* kbase = qkv + 256 + h * 32;
    const float* vbase = qkv + 512 + h * 32;
    float qv[32];
#pragma unroll
    for (int d = 0; d < 32; d += 4) {
        float4 f = *(const float4*)(qptr + d);
        qv[d] = f.x; qv[d + 1] = f.y; qv[d + 2] = f.z; qv[d + 3] = f.w;
    }
    float mx = -1e30f;
    for (int k = lane; k < 512; k += 64) {
        const float* kp = kbase + (size_t)k * 768;
        float s = 0.0f;
#pragma unroll
        for (int d = 0; d < 32; d += 4) {
            float4 f = *(const float4*)(kp + d);
            s = fmaf(qv[d], f.x, s); s = fmaf(qv[d + 1], f.y, s);
            s = fmaf(qv[d + 2], f.z, s); s = fmaf(qv[d + 3], f.w, s);
        }
        s *= 0.17677669529663687f;  // 1/sqrt(32)
        sc[w][k] = s;
        mx = fmaxf(mx, s);
    }
    mx = wave_max(mx);
    float sum = 0.0f;
    for (int k = lane; k < 512; k += 64) {
        float e = expf(sc[w][k] - mx);
        sc[w][k] = e;
        sum += e;
    }
    sum = wave_sum(sum);
    float inv = 1.0f / sum;
    __syncthreads();
    int d = lane & 31, half = lane >> 5;
    float accv = 0.0f;
    const float* vp = vbase + d;
    for (int k = half * 256; k < half * 256 + 256; ++k)
        accv = fmaf(sc[w][k], vp[(size_t)k * 768], accv);
    accv += __shfl_down(accv, 32);
    if (lane < 32) o[(size_t)q * 256 + h * 32 + d] = accv * inv;
}

// ---------------- residual + LayerNorm ----------------
__global__ void ln_res_k(float* __restrict__ x, const float* __restrict__ y,
                         const float* __restrict__ g, const float* __restrict__ b,
                         size_t goff) {
    int row = blockIdx.x, t = threadIdx.x;
    __shared__ float red[8];
    float v = x[row * 256 + t] + y[row * 256 + t];
    float s = wave_sum(v);
    if ((t & 63) == 0) red[t >> 6] = s;
    __syncthreads();
    float mean = (red[0] + red[1] + red[2] + red[3]) * (1.0f / 256.0f);
    float d = v - mean;
    float s2 = wave_sum(d * d);
    if ((t & 63) == 0) red[4 + (t >> 6)] = s2;
    __syncthreads();
    float var = (red[4] + red[5] + red[6] + red[7]) * (1.0f / 256.0f);
    x[row * 256 + t] = d * rsqrtf(var + 1e-5f) * g[goff + t] + b[goff + t];
}

// ---------------- alpha head ----------------
__global__ void alpha_k(const float* __restrict__ t1, const float* __restrict__ aW2,
                        const float* __restrict__ ab2, float* __restrict__ alphaf,
                        float* __restrict__ out_alpha) {
    int t = threadIdx.x, w = t >> 6, lane = t & 63;
    int n = blockIdx.x * 4 + w;
    const float* r = t1 + (size_t)n * 256;
    float s = 0.0f;
    for (int d = lane; d < 256; d += 64) s = fmaf(r[d], aW2[d], s);
    s = wave_sum(s);
    if (lane == 0) {
        float z = s + ab2[0];
        float a = 1.0f / (1.0f + expf(-z));
        float al = 1.2f + 2.3f * a;
        alphaf[n] = al;
        out_alpha[n] = al;
    }
}

// ---------------- CSOC kernel attention ----------------
__global__ void csock_k(const float* __restrict__ x, const float* __restrict__ alphaf,
                        float* __restrict__ latent, float* __restrict__ out_latent) {
    int i = blockIdx.x, t = threadIdx.x;
    __shared__ float wgt[512];
    __shared__ float red[4];
    float ai = alphaf[i];
    float lsum = 0.0f;
    for (int j = t; j < 512; j += 256) {
        float r = fabsf((float)(i - j)) + 1e-4f;
        float ap = 0.5f * (ai + alphaf[j]);
        float wv = powf(r, -ap) * expf(-r * 0.1f);
        wgt[j] = wv;
        lsum += wv;
    }
    float s = wave_sum(lsum);
    if ((t & 63) == 0) red[t >> 6] = s;
    __syncthreads();
    float S = red[0] + red[1] + red[2] + red[3] + 1e-8f;
    float acc = 0.0f;
    for (int j = 0; j < 512; ++j) acc = fmaf(wgt[j], x[(size_t)j * 256 + t], acc);
    float res = acc / S;
    latent[(size_t)i * 256 + t] = res;
    out_latent[(size_t)i * 256 + t] = res;
}

// ---------------- contact head ----------------
__global__ void contact_k(const float* __restrict__ h, float* __restrict__ out) {
    int i = blockIdx.x, t = threadIdx.x;
    __shared__ float hi[256];
    hi[t] = h[(size_t)i * 256 + t];
    __syncthreads();
    for (int j = t; j < 512; j += 256) {
        const float* hj = h + (size_t)j * 256;
        float s = 0.0f;
#pragma unroll 4
        for (int d = 0; d < 256; d += 4) {
            float4 a = *(const float4*)&hi[d];
            float4 b = *(const float4*)&hj[d];
            s = fmaf(a.x, b.x, s); s = fmaf(a.y, b.y, s);
            s = fmaf(a.z, b.z, s); s = fmaf(a.w, b.w, s);
        }
        out[(size_t)i * 512 + j] = 1.0f / (1.0f + expf(-s));
    }
}

// ---------------- distogram v3 (bf16 MFMA) ----------------
// out[i,j,b] = sum_d gelu(U[i,d]+V[j,d]) * dW2[b,d] + db2[b]
// Block = one i (512 blocks), 8 j-panels of 64. h-tile and dW2 in bf16 LDS,
// 16B-chunk layout [dblk(32)][row(64)] -> linear conflict-free ds_read_b128.
// 4 waves: wave w owns 16 j's; per panel 4 n-tiles x 8 k-steps of
// v_mfma_f32_16x16x32_bf16. LDS = 32KB(h) + 32KB(w2) = 64KB.
__global__ __launch_bounds__(256) void disto_k(const float* __restrict__ U,
                                               const float* __restrict__ V,
                                               const float* __restrict__ dW2,
                                               const float* __restrict__ db2,
                                               float* __restrict__ out) {
    __shared__ short hsl[32 * 64 * 8];
    __shared__ short w2l[32 * 64 * 8];
    const int t = threadIdx.x;
    const int i = blockIdx.x;
    const int row = t >> 2;      // j-local or bin (0..63)
    const int dq = t & 3;        // K-quarter (0..3)

    // dW2 -> bf16 LDS (once per block)
#pragma unroll
    for (int c = 0; c < 8; ++c) {
        int dblk = dq * 8 + c;
        int d0 = dblk * 8;
        float4 w0 = *(const float4*)&dW2[(size_t)row * 256 + d0];
        float4 w1 = *(const float4*)&dW2[(size_t)row * 256 + d0 + 4];
        uint4 p;
        p.x = f2bfu(w0.x) | ((unsigned)f2bfu(w0.y) << 16);
        p.y = f2bfu(w0.z) | ((unsigned)f2bfu(w0.w) << 16);
        p.z = f2bfu(w1.x) | ((unsigned)f2bfu(w1.y) << 16);
        p.w = f2bfu(w1.z) | ((unsigned)f2bfu(w1.w) << 16);
        *(uint4*)&w2l[(dblk * 64 + row) * 8] = p;
    }

    const int wv = t >> 6, lane = t & 63;
    const int lo = lane & 15, hi = lane >> 4;
    const int jw = wv * 16;
    // per-lane bias for the 4 n-tiles
    float dbv[4];
#pragma unroll
    for (int nt = 0; nt < 4; ++nt) dbv[nt] = db2[nt * 16 + lo];

    for (int p = 0; p < 8; ++p) {
        const int j0 = p * 64;
        // h tile: gelu(U[i,d]+V[j,d]) -> bf16 LDS
#pragma unroll
        for (int c = 0; c < 8; ++c) {
            int dblk = dq * 8 + c;
            int d0 = dblk * 8;
            float4 u0 = *(const float4*)&U[(size_t)i * 256 + d0];
            float4 u1 = *(const float4*)&U[(size_t)i * 256 + d0 + 4];
            float4 v0 = *(const float4*)&V[(size_t)(j0 + row) * 256 + d0];
            float4 v1 = *(const float4*)&V[(size_t)(j0 + row) * 256 + d0 + 4];
            float h0 = gelu_f(u0.x + v0.x), h1 = gelu_f(u0.y + v0.y);
            float h2 = gelu_f(u0.z + v0.z), h3 = gelu_f(u0.w + v0.w);
            float h4 = gelu_f(u1.x + v1.x), h5 = gelu_f(u1.y + v1.y);
            float h6 = gelu_f(u1.z + v1.z), h7 = gelu_f(u1.w + v1.w);
            uint4 q;
            q.x = f2bfu(h0) | ((unsigned)f2bfu(h1) << 16);
            q.y = f2bfu(h2) | ((unsigned)f2bfu(h3) << 16);
            q.z = f2bfu(h4) | ((unsigned)f2bfu(h5) << 16);
            q.w = f2bfu(h6) | ((unsigned)f2bfu(h7) << 16);
            *(uint4*)&hsl[(dblk * 64 + row) * 8] = q;
        }
        __syncthreads();

        f32x4 acc0 = {0.f, 0.f, 0.f, 0.f}, acc1 = acc0, acc2 = acc0, acc3 = acc0;
#pragma unroll
        for (int kk = 0; kk < 8; ++kk) {
            int db = kk * 4 + hi;
            bf16x8 a = *(bf16x8*)&hsl[(db * 64 + jw + lo) * 8];
            bf16x8 b0 = *(bf16x8*)&w2l[(db * 64 + 0 + lo) * 8];
            bf16x8 b1 = *(bf16x8*)&w2l[(db * 64 + 16 + lo) * 8];
            bf16x8 b2 = *(bf16x8*)&w2l[(db * 64 + 32 + lo) * 8];
            bf16x8 b3 = *(bf16x8*)&w2l[(db * 64 + 48 + lo) * 8];
            acc0 = __builtin_amdgcn_mfma_f32_16x16x32_bf16(a, b0, acc0, 0, 0, 0);
            acc1 = __builtin_amdgcn_mfma_f32_16x16x32_bf16(a, b1, acc1, 0, 0, 0);
            acc2 = __builtin_amdgcn_mfma_f32_16x16x32_bf16(a, b2, acc2, 0, 0, 0);
            acc3 = __builtin_amdgcn_mfma_f32_16x16x32_bf16(a, b3, acc3, 0, 0, 0);
        }
        // D layout: col = lane&15 (bin), row = (lane>>4)*4 + r (j)
#pragma unroll
        for (int r = 0; r < 4; ++r) {
            size_t jg = (size_t)i * 512 + j0 + jw + hi * 4 + r;
            out[jg * 64 + 0 + lo] = acc0[r] + dbv[0];
            out[jg * 64 + 16 + lo] = acc1[r] + dbv[1];
            out[jg * 64 + 32 + lo] = acc2[r] + dbv[2];
            out[jg * 64 + 48 + lo] = acc3[r] + dbv[3];
        }
        __syncthreads();
    }
}

// ---------------- torsion head ----------------
__global__ void torsion_k(const float* __restrict__ t1, const float* __restrict__ tW2,
                          const float* __restrict__ tb2, float* __restrict__ phi,
                          float* __restrict__ psi) {
    int t = threadIdx.x, w = t >> 6, lane = t & 63;
    int n = blockIdx.x * 4 + w;
    const float* r = t1 + (size_t)n * 256;
    float s0 = 0.0f, s1 = 0.0f;
    for (int d = lane; d < 256; d += 64) {
        float v = r[d];
        s0 = fmaf(v, tW2[d], s0);
        s1 = fmaf(v, tW2[256 + d], s1);
    }
    s0 = wave_sum(s0);
    s1 = wave_sum(s1);
    if (lane == 0) {
        phi[n] = tanhf(s0 + tb2[0]) * 3.14159265358979323846f;
        psi[n] = tanhf(s1 + tb2[1]) * 3.14159265358979323846f;
    }
}

// ---------------- diffusion coordinate init ----------------
__global__ void diff_k(const float* __restrict__ latent, const float* __restrict__ pW,
                       const float* __restrict__ pb, const float* __restrict__ noise,
                       float* __restrict__ outc) {
    int idx = blockIdx.x * 256 + threadIdx.x;
    if (idx >= 512 * 3) return;
    int n = idx / 3, a = idx % 3;
    const float* r = latent + (size_t)n * 256;
    float s = pb[a];
    for (int d = 0; d < 256; ++d) s = fmaf(r[d], pW[(size_t)a * 256 + d], s);
    float c = noise[idx];
#pragma unroll
    for (int st = 9; st >= 0; --st) {
        float at = (float)(st + 1) * 0.1f;
        c = at * c + (1.0f - at) * s;
    }
    outc[idx] = c;
}

extern "C" void kernel_launch(void* const* d_in, const int* in_sizes, int n_in,
                              void* d_out, int out_size, void* d_ws, size_t ws_size,
                              hipStream_t stream) {
    const int* tokens  = (const int*)d_in[0];
    const float* noise = (const float*)d_in[1];
    const float* emb   = (const float*)d_in[2];
    const float* Wqkv  = (const float*)d_in[3];
    const float* bqkv  = (const float*)d_in[4];
    const float* Wo    = (const float*)d_in[5];
    const float* bo    = (const float*)d_in[6];
    const float* ln1_g = (const float*)d_in[7];
    const float* ln1_b = (const float*)d_in[8];
    const float* W1    = (const float*)d_in[9];
    const float* b1    = (const float*)d_in[10];
    const float* W2    = (const float*)d_in[11];
    const float* b2    = (const float*)d_in[12];
    const float* ln2_g = (const float*)d_in[13];
    const float* ln2_b = (const float*)d_in[14];
    const float* aW1   = (const float*)d_in[15];
    const float* ab1   = (const float*)d_in[16];
    const float* aW2   = (const float*)d_in[17];
    const float* ab2   = (const float*)d_in[18];
    const float* cW    = (const float*)d_in[19];
    const float* cb    = (const float*)d_in[20];
    const float* dW1   = (const float*)d_in[21];
    const float* db1   = (const float*)d_in[22];
    const float* dW2   = (const float*)d_in[23];
    const float* db2   = (const float*)d_in[24];
    const float* tW1   = (const float*)d_in[25];
    const float* tb1   = (const float*)d_in[26];
    const float* tW2   = (const float*)d_in[27];
    const float* tb2   = (const float*)d_in[28];
    const float* pW    = (const float*)d_in[29];
    const float* pb    = (const float*)d_in[30];

    // output layout (FLOAT32, concatenated in return order)
    float* out         = (float*)d_out;
    float* out_latent  = out;               // 131072
    float* out_alpha   = out + 131072;      // 512
    float* out_contact = out + 131584;      // 262144
    float* out_disto   = out + 393728;      // 16777216
    float* out_phi     = out + 17170944;    // 512
    float* out_psi     = out + 17171456;    // 512
    float* out_c       = out + 17171968;    // 1536

    // transient scratch inside out_disto (67 MB as f32); disto_k runs LAST.
    float* scratch = out_disto;
    float* x    = scratch;            // 131072
    float* qkv  = scratch + 131072;   // 393216
    float* o    = scratch + 524288;   // 131072
    float* ffh  = scratch + 655360;   // 524288
    float* y    = scratch + 1179648;  // 131072
    float* hbuf = scratch + 1310720;  // 131072
    float* t1   = scratch + 1441792;  // 131072

    // persistent across disto_k: keep in d_ws (1.54 MB)
    float* latentf = (float*)d_ws;      // 131072
    float* U       = latentf + 131072;  // 131072
    float* Vv      = U + 131072;        // 131072
    float* alphaf  = Vv + 131072;       // 512

    embed_k<<<512, 256, 0, stream>>>(tokens, emb, x);

    for (int l = 0; l < 4; ++l) {
        gemm32<0><<<dim3(12, 16), 256, 0, stream>>>(x, Wqkv, bqkv, qkv,
                                                    512, 768, 256, 256, 0,
                                                    (size_t)l * 196608, (size_t)l * 768);
        attn_k<<<dim3(128, 8), 256, 0, stream>>>(qkv, o);
        gemm32<0><<<dim3(4, 16), 256, 0, stream>>>(o, Wo, bo, y,
                                                   512, 256, 256, 256, 0,
                                                   (size_t)l * 65536, (size_t)l * 256);
        ln_res_k<<<512, 256, 0, stream>>>(x, y, ln1_g, ln1_b, (size_t)l * 256);
        gemm32<1><<<dim3(16, 16), 256, 0, stream>>>(x, W1, b1, ffh,
                                                    512, 1024, 256, 256, 0,
                                                    (size_t)l * 262144, (size_t)l * 1024);
        gemm32<0><<<dim3(4, 16), 256, 0, stream>>>(ffh, W2, b2, y,
                                                   512, 256, 1024, 1024, 0,
                                                   (size_t)l * 262144, (size_t)l * 256);
        ln_res_k<<<512, 256, 0, stream>>>(x, y, ln2_g, ln2_b, (size_t)l * 256);
    }

    // alpha head
    gemm32<2><<<dim3(4, 16), 256, 0, stream>>>(x, aW1, ab1, t1,
                                               512, 256, 256, 256, 0, 0, 0);
    alpha_k<<<128, 256, 0, stream>>>(t1, aW2, ab2, alphaf, out_alpha);

    // CSOC kernel attention -> latent
    csock_k<<<512, 256, 0, stream>>>(x, alphaf, latentf, out_latent);

    // contact head
    gemm32<0><<<dim3(4, 16), 256, 0, stream>>>(latentf, cW, cb, hbuf,
                                               512, 256, 256, 256, 0, 0, 0);
    contact_k<<<512, 256, 0, stream>>>(hbuf, out_contact);

    // distogram first linear (separable): U = latent.dW1[:,:256]^T + db1 ; V = latent.dW1[:,256:]^T
    gemm32<0><<<dim3(4, 16), 256, 0, stream>>>(latentf, dW1, db1, U,
                                               512, 256, 256, 512, 0, 0, 0);
    gemm32<0><<<dim3(4, 16), 256, 0, stream>>>(latentf, dW1, nullptr, Vv,
                                               512, 256, 256, 512, 256, 0, 0);

    // torsion head (uses t1 scratch -> before disto_k)
    gemm32<2><<<dim3(4, 16), 256, 0, stream>>>(latentf, tW1, tb1, t1,
                                               512, 256, 256, 256, 0, 0, 0);
    torsion_k<<<128, 256, 0, stream>>>(t1, tW2, tb2, out_phi, out_psi);

    // diffusion coordinate init
    diff_k<<<6, 256, 0, stream>>>(latentf, pW, pb, noise, out_c);

    // distogram LAST: overwrites the scratch region with the real output
    disto_k<<<512, 256, 0, stream>>>(U, Vv, dW2, db2, out_disto);
}

// Round 9
// 584.492 us; speedup vs baseline: 2.3211x; 1.2357x over previous
//
#include <hip/hip_runtime.h>
#include <hip/hip_bf16.h>

typedef __attribute__((ext_vector_type(8))) short bf16x8;
typedef __attribute__((ext_vector_type(4))) float f32x4;

__device__ inline float gelu_f(float x) {
    return 0.5f * x * (1.0f + erff(x * 0.70710678118654752f));
}

__device__ inline unsigned short f2bfu(float x) {
    __hip_bfloat16 b = __float2bfloat16(x);
    return *reinterpret_cast<unsigned short*>(&b);
}

__device__ inline uint4 pack_bf8(float4 a, float4 b) {
    uint4 p;
    p.x = f2bfu(a.x) | ((unsigned)f2bfu(a.y) << 16);
    p.y = f2bfu(a.z) | ((unsigned)f2bfu(a.w) << 16);
    p.z = f2bfu(b.x) | ((unsigned)f2bfu(b.y) << 16);
    p.w = f2bfu(b.z) | ((unsigned)f2bfu(b.w) << 16);
    return p;
}

__device__ inline float wave_sum(float v) {
#pragma unroll
    for (int o = 32; o > 0; o >>= 1) v += __shfl_xor(v, o);
    return v;
}
__device__ inline float wave_max(float v) {
#pragma unroll
    for (int o = 32; o > 0; o >>= 1) v = fmaxf(v, __shfl_xor(v, o));
    return v;
}

// ---------------- embedding + positional encoding ----------------
__global__ void embed_k(const int* __restrict__ tokens, const float* __restrict__ emb,
                        float* __restrict__ x) {
    int n = blockIdx.x, t = threadIdx.x;
    float e = emb[(size_t)tokens[n] * 256 + t];
    int k = t >> 1;
    float div = expf((float)(2 * k) * (-9.210340371976184f / 256.0f));
    float arg = (float)n * div;
    x[(size_t)n * 256 + t] = e + ((t & 1) ? cosf(arg) : sinf(arg));
}

// ---------------- MFMA GEMM (bf16): C[m,n] = act(A[m,:K].W[woff+n*ldw+koff+:K] + B[boff+n]) ----------------
// 64x64 tile, 4 waves (wave w = rows w*16..+16), K-step 32, double-buffered bf16 LDS
// in 16B-chunk layout [kgroup(4)][row(64)] (disto-validated conflict-free reads).
template <int ACT>
__global__ __launch_bounds__(256) void gemm_mfma(const float* __restrict__ A,
                                                 const float* __restrict__ W,
                                                 const float* __restrict__ bias,
                                                 float* __restrict__ C,
                                                 int M, int Nn, int K, int ldw, int koff,
                                                 size_t woff, size_t boff) {
    __shared__ short Al[2][4 * 64 * 8];
    __shared__ short Wl[2][4 * 64 * 8];
    const int t = threadIdx.x;
    const int bm = blockIdx.y * 64, bn = blockIdx.x * 64;
    const int row = t >> 2, kg = t & 3;          // staging role
    const int wv = t >> 6, lane = t & 63;        // compute role
    const int lo = lane & 15, hi = lane >> 4;

    const float* aptr = A + (size_t)(bm + row) * K + kg * 8;
    const float* wptr = W + woff + (size_t)(bn + row) * ldw + koff + kg * 8;

    f32x4 acc0 = {0.f, 0.f, 0.f, 0.f}, acc1 = acc0, acc2 = acc0, acc3 = acc0;

    float4 a0 = *(const float4*)aptr;
    float4 a1 = *(const float4*)(aptr + 4);
    float4 w0 = *(const float4*)wptr;
    float4 w1 = *(const float4*)(wptr + 4);

    const int nsteps = K >> 5;
    for (int s = 0; s < nsteps; ++s) {
        const int buf = s & 1;
        *(uint4*)&Al[buf][(kg * 64 + row) * 8] = pack_bf8(a0, a1);
        *(uint4*)&Wl[buf][(kg * 64 + row) * 8] = pack_bf8(w0, w1);
        __syncthreads();
        if (s + 1 < nsteps) {
            const float* ap = aptr + (s + 1) * 32;
            const float* wp = wptr + (s + 1) * 32;
            a0 = *(const float4*)ap;  a1 = *(const float4*)(ap + 4);
            w0 = *(const float4*)wp;  w1 = *(const float4*)(wp + 4);
        }
        bf16x8 af = *(bf16x8*)&Al[buf][(hi * 64 + wv * 16 + lo) * 8];
        bf16x8 b0 = *(bf16x8*)&Wl[buf][(hi * 64 + 0 + lo) * 8];
        bf16x8 b1 = *(bf16x8*)&Wl[buf][(hi * 64 + 16 + lo) * 8];
        bf16x8 b2 = *(bf16x8*)&Wl[buf][(hi * 64 + 32 + lo) * 8];
        bf16x8 b3 = *(bf16x8*)&Wl[buf][(hi * 64 + 48 + lo) * 8];
        acc0 = __builtin_amdgcn_mfma_f32_16x16x32_bf16(af, b0, acc0, 0, 0, 0);
        acc1 = __builtin_amdgcn_mfma_f32_16x16x32_bf16(af, b1, acc1, 0, 0, 0);
        acc2 = __builtin_amdgcn_mfma_f32_16x16x32_bf16(af, b2, acc2, 0, 0, 0);
        acc3 = __builtin_amdgcn_mfma_f32_16x16x32_bf16(af, b3, acc3, 0, 0, 0);
    }

    // C layout: row = bm + wv*16 + hi*4 + r, col = bn + nt*16 + lo
    float bv0 = bias ? bias[boff + bn + 0 + lo] : 0.0f;
    float bv1 = bias ? bias[boff + bn + 16 + lo] : 0.0f;
    float bv2 = bias ? bias[boff + bn + 32 + lo] : 0.0f;
    float bv3 = bias ? bias[boff + bn + 48 + lo] : 0.0f;
#pragma unroll
    for (int r = 0; r < 4; ++r) {
        size_t rw = (size_t)(bm + wv * 16 + hi * 4 + r) * Nn + bn;
        float v0 = acc0[r] + bv0, v1 = acc1[r] + bv1, v2 = acc2[r] + bv2, v3 = acc3[r] + bv3;
        if (ACT == 1) {
            v0 = fmaxf(v0, 0.f); v1 = fmaxf(v1, 0.f); v2 = fmaxf(v2, 0.f); v3 = fmaxf(v3, 0.f);
        }
        C[rw + 0 + lo] = v0;
        C[rw + 16 + lo] = v1;
        C[rw + 32 + lo] = v2;
        C[rw + 48 + lo] = v3;
    }
}

// ---------------- tiled GEMM 32x64 (f32, for heads) ----------------
template <int ACT>
__global__ __launch_bounds__(256) void gemm32(const float* __restrict__ A,
                                              const float* __restrict__ W,
                                              const float* __restrict__ bias,
                                              float* __restrict__ C,
                                              int M, int Nn, int K, int ldw, int koff,
                                              size_t woff, size_t boff) {
    __shared__ float As[32][34];
    __shared__ float Bs[32][68];
    const int tid = threadIdx.x;
    const int tx = tid & 15, ty = tid >> 4;
    const int bm = blockIdx.y * 32, bn = blockIdx.x * 64;
    float acc[2][4] = {};
    const int ra = tid >> 3, ca = (tid & 7) * 4;
    const int rw = tid >> 2, cw = (tid & 3) * 8;
    for (int k0 = 0; k0 < K; k0 += 32) {
        float4 a0 = *(const float4*)(A + (size_t)(bm + ra) * K + k0 + ca);
        const float* wsrc = W + woff + (size_t)(bn + rw) * ldw + koff + k0 + cw;
        float4 w0 = *(const float4*)wsrc;
        float4 w1 = *(const float4*)(wsrc + 4);
        As[ca + 0][ra] = a0.x; As[ca + 1][ra] = a0.y; As[ca + 2][ra] = a0.z; As[ca + 3][ra] = a0.w;
        Bs[cw + 0][rw] = w0.x; Bs[cw + 1][rw] = w0.y; Bs[cw + 2][rw] = w0.z; Bs[cw + 3][rw] = w0.w;
        Bs[cw + 4][rw] = w1.x; Bs[cw + 5][rw] = w1.y; Bs[cw + 6][rw] = w1.z; Bs[cw + 7][rw] = w1.w;
        __syncthreads();
#pragma unroll
        for (int kk = 0; kk < 32; ++kk) {
            float a0s = As[kk][ty * 2];
            float a1s = As[kk][ty * 2 + 1];
            float4 bv = *(const float4*)&Bs[kk][tx * 4];
            acc[0][0] = fmaf(a0s, bv.x, acc[0][0]); acc[0][1] = fmaf(a0s, bv.y, acc[0][1]);
            acc[0][2] = fmaf(a0s, bv.z, acc[0][2]); acc[0][3] = fmaf(a0s, bv.w, acc[0][3]);
            acc[1][0] = fmaf(a1s, bv.x, acc[1][0]); acc[1][1] = fmaf(a1s, bv.y, acc[1][1]);
            acc[1][2] = fmaf(a1s, bv.z, acc[1][2]); acc[1][3] = fmaf(a1s, bv.w, acc[1][3]);
        }
        __syncthreads();
    }
#pragma unroll
    for (int j2 = 0; j2 < 4; ++j2) {
        int n = bn + tx * 4 + j2;
        float bv = bias ? bias[boff + n] : 0.0f;
#pragma unroll
        for (int i2 = 0; i2 < 2; ++i2) {
            float v = acc[i2][j2] + bv;
            if (ACT == 1) v = fmaxf(v, 0.0f);
            if (ACT == 2) v = gelu_f(v);
            C[(size_t)(bm + ty * 2 + i2) * Nn + n] = v;
        }
    }
}

// ---------------- attention: wave per (head, query) ----------------
__global__ __launch_bounds__(256) void attn_k(const float* __restrict__ qkv,
                                              float* __restrict__ o) {
    __shared__ float sc[4][512];
    int t = threadIdx.x;
    int w = t >> 6, lane = t & 63;
    int q = blockIdx.x * 4 + w;
    int h = blockIdx.y;
    const float* qptr = qkv + (size_t)q * 768 + h * 32;
    const float* kbase = qkv + 256 + h * 32;
    const float* vbase = qkv + 512 + h * 32;
    float qv[32];
#pragma unroll
    for (int d = 0; d < 32; d += 4) {
        float4 f = *(const float4*)(qptr + d);
        qv[d] = f.x; qv[d + 1] = f.y; qv[d + 2] = f.z; qv[d + 3] = f.w;
    }
    float mx = -1e30f;
    for (int k = lane; k < 512; k += 64) {
        const float* kp = kbase + (size_t)k * 768;
        float s = 0.0f;
#pragma unroll
        for (int d = 0; d < 32; d += 4) {
            float4 f = *(const float4*)(kp + d);
            s = fmaf(qv[d], f.x, s); s = fmaf(qv[d + 1], f.y, s);
            s = fmaf(qv[d + 2], f.z, s); s = fmaf(qv[d + 3], f.w, s);
        }
        s *= 0.17677669529663687f;  // 1/sqrt(32)
        sc[w][k] = s;
        mx = fmaxf(mx, s);
    }
    mx = wave_max(mx);
    float sum = 0.0f;
    for (int k = lane; k < 512; k += 64) {
        float e = expf(sc[w][k] - mx);
        sc[w][k] = e;
        sum += e;
    }
    sum = wave_sum(sum);
    float inv = 1.0f / sum;
    __syncthreads();
    int d = lane & 31, half = lane >> 5;
    float accv = 0.0f;
    const float* vp = vbase + d;
    for (int k = half * 256; k < half * 256 + 256; ++k)
        accv = fmaf(sc[w][k], vp[(size_t)k * 768], accv);
    accv += __shfl_down(accv, 32);
    if (lane < 32) o[(size_t)q * 256 + h * 32 + d] = accv * inv;
}

// ---------------- residual + LayerNorm ----------------
__global__ void ln_res_k(float* __restrict__ x, const float* __restrict__ y,
                         const float* __restrict__ g, const float* __restrict__ b,
                         size_t goff) {
    int row = blockIdx.x, t = threadIdx.x;
    __shared__ float red[8];
    float v = x[row * 256 + t] + y[row * 256 + t];
    float s = wave_sum(v);
    if ((t & 63) == 0) red[t >> 6] = s;
    __syncthreads();
    float mean = (red[0] + red[1] + red[2] + red[3]) * (1.0f / 256.0f);
    float d = v - mean;
    float s2 = wave_sum(d * d);
    if ((t & 63) == 0) red[4 + (t >> 6)] = s2;
    __syncthreads();
    float var = (red[4] + red[5] + red[6] + red[7]) * (1.0f / 256.0f);
    x[row * 256 + t] = d * rsqrtf(var + 1e-5f) * g[goff + t] + b[goff + t];
}

// ---------------- alpha head ----------------
__global__ void alpha_k(const float* __restrict__ t1, const float* __restrict__ aW2,
                        const float* __restrict__ ab2, float* __restrict__ alphaf,
                        float* __restrict__ out_alpha) {
    int t = threadIdx.x, w = t >> 6, lane = t & 63;
    int n = blockIdx.x * 4 + w;
    const float* r = t1 + (size_t)n * 256;
    float s = 0.0f;
    for (int d = lane; d < 256; d += 64) s = fmaf(r[d], aW2[d], s);
    s = wave_sum(s);
    if (lane == 0) {
        float z = s + ab2[0];
        float a = 1.0f / (1.0f + expf(-z));
        float al = 1.2f + 2.3f * a;
        alphaf[n] = al;
        out_alpha[n] = al;
    }
}

// ---------------- CSOC kernel attention ----------------
__global__ void csock_k(const float* __restrict__ x, const float* __restrict__ alphaf,
                        float* __restrict__ latent, float* __restrict__ out_latent) {
    int i = blockIdx.x, t = threadIdx.x;
    __shared__ float wgt[512];
    __shared__ float red[4];
    float ai = alphaf[i];
    float lsum = 0.0f;
    for (int j = t; j < 512; j += 256) {
        float r = fabsf((float)(i - j)) + 1e-4f;
        float ap = 0.5f * (ai + alphaf[j]);
        float wv = powf(r, -ap) * expf(-r * 0.1f);
        wgt[j] = wv;
        lsum += wv;
    }
    float s = wave_sum(lsum);
    if ((t & 63) == 0) red[t >> 6] = s;
    __syncthreads();
    float S = red[0] + red[1] + red[2] + red[3] + 1e-8f;
    float acc = 0.0f;
    for (int j = 0; j < 512; ++j) acc = fmaf(wgt[j], x[(size_t)j * 256 + t], acc);
    float res = acc / S;
    latent[(size_t)i * 256 + t] = res;
    out_latent[(size_t)i * 256 + t] = res;
}

// ---------------- contact head ----------------
__global__ void contact_k(const float* __restrict__ h, float* __restrict__ out) {
    int i = blockIdx.x, t = threadIdx.x;
    __shared__ float hi[256];
    hi[t] = h[(size_t)i * 256 + t];
    __syncthreads();
    for (int j = t; j < 512; j += 256) {
        const float* hj = h + (size_t)j * 256;
        float s = 0.0f;
#pragma unroll 4
        for (int d = 0; d < 256; d += 4) {
            float4 a = *(const float4*)&hi[d];
            float4 b = *(const float4*)&hj[d];
            s = fmaf(a.x, b.x, s); s = fmaf(a.y, b.y, s);
            s = fmaf(a.z, b.z, s); s = fmaf(a.w, b.w, s);
        }
        out[(size_t)i * 512 + j] = 1.0f / (1.0f + expf(-s));
    }
}

// ---------------- distogram (bf16 MFMA) ----------------
__global__ __launch_bounds__(256) void disto_k(const float* __restrict__ U,
                                               const float* __restrict__ V,
                                               const float* __restrict__ dW2,
                                               const float* __restrict__ db2,
                                               float* __restrict__ out) {
    __shared__ short hsl[32 * 64 * 8];
    __shared__ short w2l[32 * 64 * 8];
    const int t = threadIdx.x;
    const int i = blockIdx.x;
    const int row = t >> 2;
    const int dq = t & 3;

#pragma unroll
    for (int c = 0; c < 8; ++c) {
        int dblk = dq * 8 + c;
        int d0 = dblk * 8;
        float4 w0 = *(const float4*)&dW2[(size_t)row * 256 + d0];
        float4 w1 = *(const float4*)&dW2[(size_t)row * 256 + d0 + 4];
        *(uint4*)&w2l[(dblk * 64 + row) * 8] = pack_bf8(w0, w1);
    }

    const int wv = t >> 6, lane = t & 63;
    const int lo = lane & 15, hi = lane >> 4;
    const int jw = wv * 16;
    float dbv[4];
#pragma unroll
    for (int nt = 0; nt < 4; ++nt) dbv[nt] = db2[nt * 16 + lo];

    for (int p = 0; p < 8; ++p) {
        const int j0 = p * 64;
#pragma unroll
        for (int c = 0; c < 8; ++c) {
            int dblk = dq * 8 + c;
            int d0 = dblk * 8;
            float4 u0 = *(const float4*)&U[(size_t)i * 256 + d0];
            float4 u1 = *(const float4*)&U[(size_t)i * 256 + d0 + 4];
            float4 v0 = *(const float4*)&V[(size_t)(j0 + row) * 256 + d0];
            float4 v1 = *(const float4*)&V[(size_t)(j0 + row) * 256 + d0 + 4];
            float4 h0, h1;
            h0.x = gelu_f(u0.x + v0.x); h0.y = gelu_f(u0.y + v0.y);
            h0.z = gelu_f(u0.z + v0.z); h0.w = gelu_f(u0.w + v0.w);
            h1.x = gelu_f(u1.x + v1.x); h1.y = gelu_f(u1.y + v1.y);
            h1.z = gelu_f(u1.z + v1.z); h1.w = gelu_f(u1.w + v1.w);
            *(uint4*)&hsl[(dblk * 64 + row) * 8] = pack_bf8(h0, h1);
        }
        __syncthreads();

        f32x4 acc0 = {0.f, 0.f, 0.f, 0.f}, acc1 = acc0, acc2 = acc0, acc3 = acc0;
#pragma unroll
        for (int kk = 0; kk < 8; ++kk) {
            int db = kk * 4 + hi;
            bf16x8 a = *(bf16x8*)&hsl[(db * 64 + jw + lo) * 8];
            bf16x8 b0 = *(bf16x8*)&w2l[(db * 64 + 0 + lo) * 8];
            bf16x8 b1 = *(bf16x8*)&w2l[(db * 64 + 16 + lo) * 8];
            bf16x8 b2 = *(bf16x8*)&w2l[(db * 64 + 32 + lo) * 8];
            bf16x8 b3 = *(bf16x8*)&w2l[(db * 64 + 48 + lo) * 8];
            acc0 = __builtin_amdgcn_mfma_f32_16x16x32_bf16(a, b0, acc0, 0, 0, 0);
            acc1 = __builtin_amdgcn_mfma_f32_16x16x32_bf16(a, b1, acc1, 0, 0, 0);
            acc2 = __builtin_amdgcn_mfma_f32_16x16x32_bf16(a, b2, acc2, 0, 0, 0);
            acc3 = __builtin_amdgcn_mfma_f32_16x16x32_bf16(a, b3, acc3, 0, 0, 0);
        }
#pragma unroll
        for (int r = 0; r < 4; ++r) {
            size_t jg = (size_t)i * 512 + j0 + jw + hi * 4 + r;
            out[jg * 64 + 0 + lo] = acc0[r] + dbv[0];
            out[jg * 64 + 16 + lo] = acc1[r] + dbv[1];
            out[jg * 64 + 32 + lo] = acc2[r] + dbv[2];
            out[jg * 64 + 48 + lo] = acc3[r] + dbv[3];
        }
        __syncthreads();
    }
}

// ---------------- torsion head ----------------
__global__ void torsion_k(const float* __restrict__ t1, const float* __restrict__ tW2,
                          const float* __restrict__ tb2, float* __restrict__ phi,
                          float* __restrict__ psi) {
    int t = threadIdx.x, w = t >> 6, lane = t & 63;
    int n = blockIdx.x * 4 + w;
    const float* r = t1 + (size_t)n * 256;
    float s0 = 0.0f, s1 = 0.0f;
    for (int d = lane; d < 256; d += 64) {
        float v = r[d];
        s0 = fmaf(v, tW2[d], s0);
        s1 = fmaf(v, tW2[256 + d], s1);
    }
    s0 = wave_sum(s0);
    s1 = wave_sum(s1);
    if (lane == 0) {
        phi[n] = tanhf(s0 + tb2[0]) * 3.14159265358979323846f;
        psi[n] = tanhf(s1 + tb2[1]) * 3.14159265358979323846f;
    }
}

// ---------------- diffusion coordinate init ----------------
__global__ void diff_k(const float* __restrict__ latent, const float* __restrict__ pW,
                       const float* __restrict__ pb, const float* __restrict__ noise,
                       float* __restrict__ outc) {
    int idx = blockIdx.x * 256 + threadIdx.x;
    if (idx >= 512 * 3) return;
    int n = idx / 3, a = idx % 3;
    const float* r = latent + (size_t)n * 256;
    float s = pb[a];
    for (int d = 0; d < 256; ++d) s = fmaf(r[d], pW[(size_t)a * 256 + d], s);
    float c = noise[idx];
#pragma unroll
    for (int st = 9; st >= 0; --st) {
        float at = (float)(st + 1) * 0.1f;
        c = at * c + (1.0f - at) * s;
    }
    outc[idx] = c;
}

extern "C" void kernel_launch(void* const* d_in, const int* in_sizes, int n_in,
                              void* d_out, int out_size, void* d_ws, size_t ws_size,
                              hipStream_t stream) {
    const int* tokens  = (const int*)d_in[0];
    const float* noise = (const float*)d_in[1];
    const float* emb   = (const float*)d_in[2];
    const float* Wqkv  = (const float*)d_in[3];
    const float* bqkv  = (const float*)d_in[4];
    const float* Wo    = (const float*)d_in[5];
    const float* bo    = (const float*)d_in[6];
    const float* ln1_g = (const float*)d_in[7];
    const float* ln1_b = (const float*)d_in[8];
    const float* W1    = (const float*)d_in[9];
    const float* b1    = (const float*)d_in[10];
    const float* W2    = (const float*)d_in[11];
    const float* b2    = (const float*)d_in[12];
    const float* ln2_g = (const float*)d_in[13];
    const float* ln2_b = (const float*)d_in[14];
    const float* aW1   = (const float*)d_in[15];
    const float* ab1   = (const float*)d_in[16];
    const float* aW2   = (const float*)d_in[17];
    const float* ab2   = (const float*)d_in[18];
    const float* cW    = (const float*)d_in[19];
    const float* cb    = (const float*)d_in[20];
    const float* dW1   = (const float*)d_in[21];
    const float* db1   = (const float*)d_in[22];
    const float* dW2   = (const float*)d_in[23];
    const float* db2   = (const float*)d_in[24];
    const float* tW1   = (const float*)d_in[25];
    const float* tb1   = (const float*)d_in[26];
    const float* tW2   = (const float*)d_in[27];
    const float* tb2   = (const float*)d_in[28];
    const float* pW    = (const float*)d_in[29];
    const float* pb    = (const float*)d_in[30];

    // output layout (FLOAT32, concatenated in return order)
    float* out         = (float*)d_out;
    float* out_latent  = out;               // 131072
    float* out_alpha   = out + 131072;      // 512
    float* out_contact = out + 131584;      // 262144
    float* out_disto   = out + 393728;      // 16777216
    float* out_phi     = out + 17170944;    // 512
    float* out_psi     = out + 17171456;    // 512
    float* out_c       = out + 17171968;    // 1536

    // transient scratch inside out_disto (67 MB as f32); disto_k runs LAST.
    float* scratch = out_disto;
    float* x    = scratch;            // 131072
    float* qkv  = scratch + 131072;   // 393216
    float* o    = scratch + 524288;   // 131072
    float* ffh  = scratch + 655360;   // 524288
    float* y    = scratch + 1179648;  // 131072
    float* hbuf = scratch + 1310720;  // 131072
    float* t1   = scratch + 1441792;  // 131072

    // persistent across disto_k: keep in d_ws (1.54 MB)
    float* latentf = (float*)d_ws;      // 131072
    float* U       = latentf + 131072;  // 131072
    float* Vv      = U + 131072;        // 131072
    float* alphaf  = Vv + 131072;       // 512

    embed_k<<<512, 256, 0, stream>>>(tokens, emb, x);

    for (int l = 0; l < 4; ++l) {
        gemm_mfma<0><<<dim3(12, 8), 256, 0, stream>>>(x, Wqkv, bqkv, qkv,
                                                      512, 768, 256, 256, 0,
                                                      (size_t)l * 196608, (size_t)l * 768);
        attn_k<<<dim3(128, 8), 256, 0, stream>>>(qkv, o);
        gemm_mfma<0><<<dim3(4, 8), 256, 0, stream>>>(o, Wo, bo, y,
                                                     512, 256, 256, 256, 0,
                                                     (size_t)l * 65536, (size_t)l * 256);
        ln_res_k<<<512, 256, 0, stream>>>(x, y, ln1_g, ln1_b, (size_t)l * 256);
        gemm_mfma<1><<<dim3(16, 8), 256, 0, stream>>>(x, W1, b1, ffh,
                                                      512, 1024, 256, 256, 0,
                                                      (size_t)l * 262144, (size_t)l * 1024);
        gemm_mfma<0><<<dim3(4, 8), 256, 0, stream>>>(ffh, W2, b2, y,
                                                     512, 256, 1024, 1024, 0,
                                                     (size_t)l * 262144, (size_t)l * 256);
        ln_res_k<<<512, 256, 0, stream>>>(x, y, ln2_g, ln2_b, (size_t)l * 256);
    }

    // alpha head (f32)
    gemm32<2><<<dim3(4, 16), 256, 0, stream>>>(x, aW1, ab1, t1,
                                               512, 256, 256, 256, 0, 0, 0);
    alpha_k<<<128, 256, 0, stream>>>(t1, aW2, ab2, alphaf, out_alpha);

    // CSOC kernel attention -> latent
    csock_k<<<512, 256, 0, stream>>>(x, alphaf, latentf, out_latent);

    // contact head (f32)
    gemm32<0><<<dim3(4, 16), 256, 0, stream>>>(latentf, cW, cb, hbuf,
                                               512, 256, 256, 256, 0, 0, 0);
    contact_k<<<512, 256, 0, stream>>>(hbuf, out_contact);

    // distogram first linear (separable, f32)
    gemm32<0><<<dim3(4, 16), 256, 0, stream>>>(latentf, dW1, db1, U,
                                               512, 256, 256, 512, 0, 0, 0);
    gemm32<0><<<dim3(4, 16), 256, 0, stream>>>(latentf, dW1, nullptr, Vv,
                                               512, 256, 256, 512, 256, 0, 0);

    // torsion head (f32; uses t1 scratch -> before disto_k)
    gemm32<2><<<dim3(4, 16), 256, 0, stream>>>(latentf, tW1, tb1, t1,
                                               512, 256, 256, 256, 0, 0, 0);
    torsion_k<<<128, 256, 0, stream>>>(t1, tW2, tb2, out_phi, out_psi);

    // diffusion coordinate init
    diff_k<<<6, 256, 0, stream>>>(latentf, pW, pb, noise, out_c);

    // distogram LAST: overwrites the scratch region with the real output
    disto_k<<<512, 256, 0, stream>>>(U, Vv, dW2, db2, out_disto);
}

// Round 10
// 530.291 us; speedup vs baseline: 2.5583x; 1.1022x over previous
//
#include <hip/hip_runtime.h>
#include <hip/hip_bf16.h>

typedef __attribute__((ext_vector_type(8))) short bf16x8;
typedef __attribute__((ext_vector_type(4))) float f32x4;
typedef unsigned short ushort;

__device__ inline float gelu_f(float x) {
    return 0.5f * x * (1.0f + erff(x * 0.70710678118654752f));
}

__device__ inline ushort f2bfu(float x) {
    __hip_bfloat16 b = __float2bfloat16(x);
    return *reinterpret_cast<ushort*>(&b);
}

__device__ inline uint4 pack_bf8(float4 a, float4 b) {
    uint4 p;
    p.x = f2bfu(a.x) | ((unsigned)f2bfu(a.y) << 16);
    p.y = f2bfu(a.z) | ((unsigned)f2bfu(a.w) << 16);
    p.z = f2bfu(b.x) | ((unsigned)f2bfu(b.y) << 16);
    p.w = f2bfu(b.z) | ((unsigned)f2bfu(b.w) << 16);
    return p;
}

__device__ inline float wave_sum(float v) {
#pragma unroll
    for (int o = 32; o > 0; o >>= 1) v += __shfl_xor(v, o);
    return v;
}
__device__ inline float wave_max(float v) {
#pragma unroll
    for (int o = 32; o > 0; o >>= 1) v = fmaxf(v, __shfl_xor(v, o));
    return v;
}

// ---------------- weight conversion: all transformer weights -> bf16, once ----------------
// dst layout: Wqkvb [0,786432) | Wob [786432,1048576) | W1b [1048576,2097152) | W2b [2097152,3145728)
__global__ void convw_k(const float* __restrict__ Wqkv, const float* __restrict__ Wo,
                        const float* __restrict__ W1, const float* __restrict__ W2,
                        ushort* __restrict__ dst) {
    size_t i = ((size_t)blockIdx.x * 256 + threadIdx.x) * 8;
    if (i >= 3145728) return;
    const float* src;
    size_t off;
    if (i < 786432)       { src = Wqkv; off = i; }
    else if (i < 1048576) { src = Wo;   off = i - 786432; }
    else if (i < 2097152) { src = W1;   off = i - 1048576; }
    else                  { src = W2;   off = i - 2097152; }
    float4 f0 = *(const float4*)&src[off];
    float4 f1 = *(const float4*)&src[off + 4];
    *(uint4*)&dst[i] = pack_bf8(f0, f1);
}

// ---------------- embedding + positional encoding ----------------
__global__ void embed_k(const int* __restrict__ tokens, const float* __restrict__ emb,
                        float* __restrict__ x, ushort* __restrict__ xb) {
    int n = blockIdx.x, t = threadIdx.x;
    float e = emb[(size_t)tokens[n] * 256 + t];
    int k = t >> 1;
    float div = expf((float)(2 * k) * (-9.210340371976184f / 256.0f));
    float arg = (float)n * div;
    float v = e + ((t & 1) ? cosf(arg) : sinf(arg));
    x[(size_t)n * 256 + t] = v;
    xb[(size_t)n * 256 + t] = f2bfu(v);
}

// ---------------- MFMA GEMM, bf16 in / {f32 or bf16} out ----------------
// 64x64 tile, 4 waves, K-step 32, double-buffered LDS; staging is a pure
// uint4 copy (A/W already bf16). Chunk t*16B == [kgroup(4)][row(64)] layout.
template <int ACT, int OBF>
__global__ __launch_bounds__(256) void gemm_bf(const ushort* __restrict__ A,
                                               const ushort* __restrict__ Wb,
                                               const float* __restrict__ bias,
                                               float* __restrict__ C,
                                               ushort* __restrict__ Cb,
                                               int Nn, int K, int lda, int ldw,
                                               size_t woff, size_t boff) {
    __shared__ ushort Al[2][2048];
    __shared__ ushort Wl[2][2048];
    const int t = threadIdx.x;
    const int bm = blockIdx.y * 64, bn = blockIdx.x * 64;
    const int lane = t & 63, wv = t >> 6;
    const int lo = lane & 15, hi = lane >> 4;

    const ushort* aptr = A + (size_t)(bm + lane) * lda + wv * 8;
    const ushort* wptr = Wb + woff + (size_t)(bn + lane) * ldw + wv * 8;

    f32x4 acc0 = {0.f, 0.f, 0.f, 0.f}, acc1 = acc0, acc2 = acc0, acc3 = acc0;
    uint4 a = *(const uint4*)aptr;
    uint4 w = *(const uint4*)wptr;
    const int nsteps = K >> 5;
    for (int s = 0; s < nsteps; ++s) {
        const int buf = s & 1;
        *(uint4*)&Al[buf][t * 8] = a;
        *(uint4*)&Wl[buf][t * 8] = w;
        __syncthreads();
        if (s + 1 < nsteps) {
            a = *(const uint4*)(aptr + (s + 1) * 32);
            w = *(const uint4*)(wptr + (s + 1) * 32);
        }
        bf16x8 af = *(bf16x8*)&Al[buf][(hi * 64 + wv * 16 + lo) * 8];
        bf16x8 b0 = *(bf16x8*)&Wl[buf][(hi * 64 + 0 + lo) * 8];
        bf16x8 b1 = *(bf16x8*)&Wl[buf][(hi * 64 + 16 + lo) * 8];
        bf16x8 b2 = *(bf16x8*)&Wl[buf][(hi * 64 + 32 + lo) * 8];
        bf16x8 b3 = *(bf16x8*)&Wl[buf][(hi * 64 + 48 + lo) * 8];
        acc0 = __builtin_amdgcn_mfma_f32_16x16x32_bf16(af, b0, acc0, 0, 0, 0);
        acc1 = __builtin_amdgcn_mfma_f32_16x16x32_bf16(af, b1, acc1, 0, 0, 0);
        acc2 = __builtin_amdgcn_mfma_f32_16x16x32_bf16(af, b2, acc2, 0, 0, 0);
        acc3 = __builtin_amdgcn_mfma_f32_16x16x32_bf16(af, b3, acc3, 0, 0, 0);
    }

    float bv0 = bias ? bias[boff + bn + 0 + lo] : 0.0f;
    float bv1 = bias ? bias[boff + bn + 16 + lo] : 0.0f;
    float bv2 = bias ? bias[boff + bn + 32 + lo] : 0.0f;
    float bv3 = bias ? bias[boff + bn + 48 + lo] : 0.0f;
#pragma unroll
    for (int r = 0; r < 4; ++r) {
        size_t rw = (size_t)(bm + wv * 16 + hi * 4 + r) * Nn + bn;
        float v0 = acc0[r] + bv0, v1 = acc1[r] + bv1, v2 = acc2[r] + bv2, v3 = acc3[r] + bv3;
        if (ACT == 1) {
            v0 = fmaxf(v0, 0.f); v1 = fmaxf(v1, 0.f); v2 = fmaxf(v2, 0.f); v3 = fmaxf(v3, 0.f);
        }
        if (OBF) {
            Cb[rw + 0 + lo] = f2bfu(v0);
            Cb[rw + 16 + lo] = f2bfu(v1);
            Cb[rw + 32 + lo] = f2bfu(v2);
            Cb[rw + 48 + lo] = f2bfu(v3);
        } else {
            C[rw + 0 + lo] = v0;
            C[rw + 16 + lo] = v1;
            C[rw + 32 + lo] = v2;
            C[rw + 48 + lo] = v3;
        }
    }
}

// ---------------- tiled GEMM 32x64 (f32, for heads) ----------------
template <int ACT>
__global__ __launch_bounds__(256) void gemm32(const float* __restrict__ A,
                                              const float* __restrict__ W,
                                              const float* __restrict__ bias,
                                              float* __restrict__ C,
                                              int M, int Nn, int K, int ldw, int koff,
                                              size_t woff, size_t boff) {
    __shared__ float As[32][34];
    __shared__ float Bs[32][68];
    const int tid = threadIdx.x;
    const int tx = tid & 15, ty = tid >> 4;
    const int bm = blockIdx.y * 32, bn = blockIdx.x * 64;
    float acc[2][4] = {};
    const int ra = tid >> 3, ca = (tid & 7) * 4;
    const int rw = tid >> 2, cw = (tid & 3) * 8;
    for (int k0 = 0; k0 < K; k0 += 32) {
        float4 a0 = *(const float4*)(A + (size_t)(bm + ra) * K + k0 + ca);
        const float* wsrc = W + woff + (size_t)(bn + rw) * ldw + koff + k0 + cw;
        float4 w0 = *(const float4*)wsrc;
        float4 w1 = *(const float4*)(wsrc + 4);
        As[ca + 0][ra] = a0.x; As[ca + 1][ra] = a0.y; As[ca + 2][ra] = a0.z; As[ca + 3][ra] = a0.w;
        Bs[cw + 0][rw] = w0.x; Bs[cw + 1][rw] = w0.y; Bs[cw + 2][rw] = w0.z; Bs[cw + 3][rw] = w0.w;
        Bs[cw + 4][rw] = w1.x; Bs[cw + 5][rw] = w1.y; Bs[cw + 6][rw] = w1.z; Bs[cw + 7][rw] = w1.w;
        __syncthreads();
#pragma unroll
        for (int kk = 0; kk < 32; ++kk) {
            float a0s = As[kk][ty * 2];
            float a1s = As[kk][ty * 2 + 1];
            float4 bv = *(const float4*)&Bs[kk][tx * 4];
            acc[0][0] = fmaf(a0s, bv.x, acc[0][0]); acc[0][1] = fmaf(a0s, bv.y, acc[0][1]);
            acc[0][2] = fmaf(a0s, bv.z, acc[0][2]); acc[0][3] = fmaf(a0s, bv.w, acc[0][3]);
            acc[1][0] = fmaf(a1s, bv.x, acc[1][0]); acc[1][1] = fmaf(a1s, bv.y, acc[1][1]);
            acc[1][2] = fmaf(a1s, bv.z, acc[1][2]); acc[1][3] = fmaf(a1s, bv.w, acc[1][3]);
        }
        __syncthreads();
    }
#pragma unroll
    for (int j2 = 0; j2 < 4; ++j2) {
        int n = bn + tx * 4 + j2;
        float bv = bias ? bias[boff + n] : 0.0f;
#pragma unroll
        for (int i2 = 0; i2 < 2; ++i2) {
            float v = acc[i2][j2] + bv;
            if (ACT == 1) v = fmaxf(v, 0.0f);
            if (ACT == 2) v = gelu_f(v);
            C[(size_t)(bm + ty * 2 + i2) * Nn + n] = v;
        }
    }
}

// ---------------- attention: wave per (head, query), bf16 output ----------------
__global__ __launch_bounds__(256) void attn_k(const float* __restrict__ qkv,
                                              ushort* __restrict__ ob) {
    __shared__ float sc[4][512];
    int t = threadIdx.x;
    int w = t >> 6, lane = t & 63;
    int q = blockIdx.x * 4 + w;
    int h = blockIdx.y;
    const float* qptr = qkv + (size_t)q * 768 + h * 32;
    const float* kbase = qkv + 256 + h * 32;
    const float* vbase = qkv + 512 + h * 32;
    float qv[32];
#pragma unroll
    for (int d = 0; d < 32; d += 4) {
        float4 f = *(const float4*)(qptr + d);
        qv[d] = f.x; qv[d + 1] = f.y; qv[d + 2] = f.z; qv[d + 3] = f.w;
    }
    float mx = -1e30f;
    for (int k = lane; k < 512; k += 64) {
        const float* kp = kbase + (size_t)k * 768;
        float s = 0.0f;
#pragma unroll
        for (int d = 0; d < 32; d += 4) {
            float4 f = *(const float4*)(kp + d);
            s = fmaf(qv[d], f.x, s); s = fmaf(qv[d + 1], f.y, s);
            s = fmaf(qv[d + 2], f.z, s); s = fmaf(qv[d + 3], f.w, s);
        }
        s *= 0.17677669529663687f;  // 1/sqrt(32)
        sc[w][k] = s;
        mx = fmaxf(mx, s);
    }
    mx = wave_max(mx);
    float sum = 0.0f;
    for (int k = lane; k < 512; k += 64) {
        float e = expf(sc[w][k] - mx);
        sc[w][k] = e;
        sum += e;
    }
    sum = wave_sum(sum);
    float inv = 1.0f / sum;
    __syncthreads();
    int d = lane & 31, half = lane >> 5;
    const float* vp = vbase + d;
    const int kb = half * 256;
    float a0 = 0.f, a1 = 0.f, a2 = 0.f, a3 = 0.f;
    for (int k = kb; k < kb + 256; k += 4) {
        a0 = fmaf(sc[w][k], vp[(size_t)k * 768], a0);
        a1 = fmaf(sc[w][k + 1], vp[(size_t)(k + 1) * 768], a1);
        a2 = fmaf(sc[w][k + 2], vp[(size_t)(k + 2) * 768], a2);
        a3 = fmaf(sc[w][k + 3], vp[(size_t)(k + 3) * 768], a3);
    }
    float accv = (a0 + a1) + (a2 + a3);
    accv += __shfl_down(accv, 32);
    if (lane < 32) ob[(size_t)q * 256 + h * 32 + d] = f2bfu(accv * inv);
}

// ---------------- residual + LayerNorm (f32 + bf16 copy) ----------------
__global__ void ln_res_k(float* __restrict__ x, const float* __restrict__ y,
                         const float* __restrict__ g, const float* __restrict__ b,
                         size_t goff, ushort* __restrict__ xb) {
    int row = blockIdx.x, t = threadIdx.x;
    __shared__ float red[8];
    float v = x[row * 256 + t] + y[row * 256 + t];
    float s = wave_sum(v);
    if ((t & 63) == 0) red[t >> 6] = s;
    __syncthreads();
    float mean = (red[0] + red[1] + red[2] + red[3]) * (1.0f / 256.0f);
    float d = v - mean;
    float s2 = wave_sum(d * d);
    if ((t & 63) == 0) red[4 + (t >> 6)] = s2;
    __syncthreads();
    float var = (red[4] + red[5] + red[6] + red[7]) * (1.0f / 256.0f);
    float res = d * rsqrtf(var + 1e-5f) * g[goff + t] + b[goff + t];
    x[row * 256 + t] = res;
    xb[row * 256 + t] = f2bfu(res);
}

// ---------------- alpha head ----------------
__global__ void alpha_k(const float* __restrict__ t1, const float* __restrict__ aW2,
                        const float* __restrict__ ab2, float* __restrict__ alphaf,
                        float* __restrict__ out_alpha) {
    int t = threadIdx.x, w = t >> 6, lane = t & 63;
    int n = blockIdx.x * 4 + w;
    const float* r = t1 + (size_t)n * 256;
    float s = 0.0f;
    for (int d = lane; d < 256; d += 64) s = fmaf(r[d], aW2[d], s);
    s = wave_sum(s);
    if (lane == 0) {
        float z = s + ab2[0];
        float a = 1.0f / (1.0f + expf(-z));
        float al = 1.2f + 2.3f * a;
        alphaf[n] = al;
        out_alpha[n] = al;
    }
}

// ---------------- CSOC kernel attention ----------------
__global__ void csock_k(const float* __restrict__ x, const float* __restrict__ alphaf,
                        float* __restrict__ latent, float* __restrict__ out_latent) {
    int i = blockIdx.x, t = threadIdx.x;
    __shared__ float wgt[512];
    __shared__ float red[4];
    float ai = alphaf[i];
    float lsum = 0.0f;
    for (int j = t; j < 512; j += 256) {
        float r = fabsf((float)(i - j)) + 1e-4f;
        float ap = 0.5f * (ai + alphaf[j]);
        float wv = powf(r, -ap) * expf(-r * 0.1f);
        wgt[j] = wv;
        lsum += wv;
    }
    float s = wave_sum(lsum);
    if ((t & 63) == 0) red[t >> 6] = s;
    __syncthreads();
    float S = red[0] + red[1] + red[2] + red[3] + 1e-8f;
    float acc = 0.0f;
    for (int j = 0; j < 512; ++j) acc = fmaf(wgt[j], x[(size_t)j * 256 + t], acc);
    float res = acc / S;
    latent[(size_t)i * 256 + t] = res;
    out_latent[(size_t)i * 256 + t] = res;
}

// ---------------- contact head ----------------
__global__ void contact_k(const float* __restrict__ h, float* __restrict__ out) {
    int i = blockIdx.x, t = threadIdx.x;
    __shared__ float hi[256];
    hi[t] = h[(size_t)i * 256 + t];
    __syncthreads();
    for (int j = t; j < 512; j += 256) {
        const float* hj = h + (size_t)j * 256;
        float s = 0.0f;
#pragma unroll 4
        for (int d = 0; d < 256; d += 4) {
            float4 a = *(const float4*)&hi[d];
            float4 b = *(const float4*)&hj[d];
            s = fmaf(a.x, b.x, s); s = fmaf(a.y, b.y, s);
            s = fmaf(a.z, b.z, s); s = fmaf(a.w, b.w, s);
        }
        out[(size_t)i * 512 + j] = 1.0f / (1.0f + expf(-s));
    }
}

// ---------------- distogram (bf16 MFMA) ----------------
__global__ __launch_bounds__(256) void disto_k(const float* __restrict__ U,
                                               const float* __restrict__ V,
                                               const float* __restrict__ dW2,
                                               const float* __restrict__ db2,
                                               float* __restrict__ out) {
    __shared__ short hsl[32 * 64 * 8];
    __shared__ short w2l[32 * 64 * 8];
    const int t = threadIdx.x;
    const int i = blockIdx.x;
    const int row = t >> 2;
    const int dq = t & 3;

#pragma unroll
    for (int c = 0; c < 8; ++c) {
        int dblk = dq * 8 + c;
        int d0 = dblk * 8;
        float4 w0 = *(const float4*)&dW2[(size_t)row * 256 + d0];
        float4 w1 = *(const float4*)&dW2[(size_t)row * 256 + d0 + 4];
        *(uint4*)&w2l[(dblk * 64 + row) * 8] = pack_bf8(w0, w1);
    }

    const int wv = t >> 6, lane = t & 63;
    const int lo = lane & 15, hi = lane >> 4;
    const int jw = wv * 16;
    float dbv[4];
#pragma unroll
    for (int nt = 0; nt < 4; ++nt) dbv[nt] = db2[nt * 16 + lo];

    for (int p = 0; p < 8; ++p) {
        const int j0 = p * 64;
#pragma unroll
        for (int c = 0; c < 8; ++c) {
            int dblk = dq * 8 + c;
            int d0 = dblk * 8;
            float4 u0 = *(const float4*)&U[(size_t)i * 256 + d0];
            float4 u1 = *(const float4*)&U[(size_t)i * 256 + d0 + 4];
            float4 v0 = *(const float4*)&V[(size_t)(j0 + row) * 256 + d0];
            float4 v1 = *(const float4*)&V[(size_t)(j0 + row) * 256 + d0 + 4];
            float4 h0, h1;
            h0.x = gelu_f(u0.x + v0.x); h0.y = gelu_f(u0.y + v0.y);
            h0.z = gelu_f(u0.z + v0.z); h0.w = gelu_f(u0.w + v0.w);
            h1.x = gelu_f(u1.x + v1.x); h1.y = gelu_f(u1.y + v1.y);
            h1.z = gelu_f(u1.z + v1.z); h1.w = gelu_f(u1.w + v1.w);
            *(uint4*)&hsl[(dblk * 64 + row) * 8] = pack_bf8(h0, h1);
        }
        __syncthreads();

        f32x4 acc0 = {0.f, 0.f, 0.f, 0.f}, acc1 = acc0, acc2 = acc0, acc3 = acc0;
#pragma unroll
        for (int kk = 0; kk < 8; ++kk) {
            int db = kk * 4 + hi;
            bf16x8 a = *(bf16x8*)&hsl[(db * 64 + jw + lo) * 8];
            bf16x8 b0 = *(bf16x8*)&w2l[(db * 64 + 0 + lo) * 8];
            bf16x8 b1 = *(bf16x8*)&w2l[(db * 64 + 16 + lo) * 8];
            bf16x8 b2 = *(bf16x8*)&w2l[(db * 64 + 32 + lo) * 8];
            bf16x8 b3 = *(bf16x8*)&w2l[(db * 64 + 48 + lo) * 8];
            acc0 = __builtin_amdgcn_mfma_f32_16x16x32_bf16(a, b0, acc0, 0, 0, 0);
            acc1 = __builtin_amdgcn_mfma_f32_16x16x32_bf16(a, b1, acc1, 0, 0, 0);
            acc2 = __builtin_amdgcn_mfma_f32_16x16x32_bf16(a, b2, acc2, 0, 0, 0);
            acc3 = __builtin_amdgcn_mfma_f32_16x16x32_bf16(a, b3, acc3, 0, 0, 0);
        }
#pragma unroll
        for (int r = 0; r < 4; ++r) {
            size_t jg = (size_t)i * 512 + j0 + jw + hi * 4 + r;
            out[jg * 64 + 0 + lo] = acc0[r] + dbv[0];
            out[jg * 64 + 16 + lo] = acc1[r] + dbv[1];
            out[jg * 64 + 32 + lo] = acc2[r] + dbv[2];
            out[jg * 64 + 48 + lo] = acc3[r] + dbv[3];
        }
        __syncthreads();
    }
}

// ---------------- torsion head ----------------
__global__ void torsion_k(const float* __restrict__ t1, const float* __restrict__ tW2,
                          const float* __restrict__ tb2, float* __restrict__ phi,
                          float* __restrict__ psi) {
    int t = threadIdx.x, w = t >> 6, lane = t & 63;
    int n = blockIdx.x * 4 + w;
    const float* r = t1 + (size_t)n * 256;
    float s0 = 0.0f, s1 = 0.0f;
    for (int d = lane; d < 256; d += 64) {
        float v = r[d];
        s0 = fmaf(v, tW2[d], s0);
        s1 = fmaf(v, tW2[256 + d], s1);
    }
    s0 = wave_sum(s0);
    s1 = wave_sum(s1);
    if (lane == 0) {
        phi[n] = tanhf(s0 + tb2[0]) * 3.14159265358979323846f;
        psi[n] = tanhf(s1 + tb2[1]) * 3.14159265358979323846f;
    }
}

// ---------------- diffusion coordinate init ----------------
__global__ void diff_k(const float* __restrict__ latent, const float* __restrict__ pW,
                       const float* __restrict__ pb, const float* __restrict__ noise,
                       float* __restrict__ outc) {
    int idx = blockIdx.x * 256 + threadIdx.x;
    if (idx >= 512 * 3) return;
    int n = idx / 3, a = idx % 3;
    const float* r = latent + (size_t)n * 256;
    float s = pb[a];
    for (int d = 0; d < 256; ++d) s = fmaf(r[d], pW[(size_t)a * 256 + d], s);
    float c = noise[idx];
#pragma unroll
    for (int st = 9; st >= 0; --st) {
        float at = (float)(st + 1) * 0.1f;
        c = at * c + (1.0f - at) * s;
    }
    outc[idx] = c;
}

extern "C" void kernel_launch(void* const* d_in, const int* in_sizes, int n_in,
                              void* d_out, int out_size, void* d_ws, size_t ws_size,
                              hipStream_t stream) {
    const int* tokens  = (const int*)d_in[0];
    const float* noise = (const float*)d_in[1];
    const float* emb   = (const float*)d_in[2];
    const float* Wqkv  = (const float*)d_in[3];
    const float* bqkv  = (const float*)d_in[4];
    const float* Wo    = (const float*)d_in[5];
    const float* bo    = (const float*)d_in[6];
    const float* ln1_g = (const float*)d_in[7];
    const float* ln1_b = (const float*)d_in[8];
    const float* W1    = (const float*)d_in[9];
    const float* b1    = (const float*)d_in[10];
    const float* W2    = (const float*)d_in[11];
    const float* b2    = (const float*)d_in[12];
    const float* ln2_g = (const float*)d_in[13];
    const float* ln2_b = (const float*)d_in[14];
    const float* aW1   = (const float*)d_in[15];
    const float* ab1   = (const float*)d_in[16];
    const float* aW2   = (const float*)d_in[17];
    const float* ab2   = (const float*)d_in[18];
    const float* cW    = (const float*)d_in[19];
    const float* cb    = (const float*)d_in[20];
    const float* dW1   = (const float*)d_in[21];
    const float* db1   = (const float*)d_in[22];
    const float* dW2   = (const float*)d_in[23];
    const float* db2   = (const float*)d_in[24];
    const float* tW1   = (const float*)d_in[25];
    const float* tb1   = (const float*)d_in[26];
    const float* tW2   = (const float*)d_in[27];
    const float* tb2   = (const float*)d_in[28];
    const float* pW    = (const float*)d_in[29];
    const float* pb    = (const float*)d_in[30];

    // output layout (FLOAT32, concatenated in return order)
    float* out         = (float*)d_out;
    float* out_latent  = out;               // 131072
    float* out_alpha   = out + 131072;      // 512
    float* out_contact = out + 131584;      // 262144
    float* out_disto   = out + 393728;      // 16777216
    float* out_phi     = out + 17170944;    // 512
    float* out_psi     = out + 17171456;    // 512
    float* out_c       = out + 17171968;    // 1536

    // transient scratch inside out_disto (67 MB as f32); disto_k runs LAST and
    // reads only U/V (d_ws) + weights while overwriting this region.
    float* scratch = out_disto;
    float* x    = scratch;             // 131072 f32
    float* qkv  = scratch + 131072;    // 393216 f32
    float* y    = scratch + 1179648;   // 131072 f32
    float* hbuf = scratch + 1310720;   // 131072 f32
    float* t1   = scratch + 1441792;   // 131072 f32
    ushort* wb   = (ushort*)(scratch + 2000000);  // 3145728 bf16 (1.57M f32 slots)
    ushort* xb   = (ushort*)(scratch + 3600000);  // 131072 bf16
    ushort* ob   = (ushort*)(scratch + 3700000);  // 131072 bf16
    ushort* ffhb = (ushort*)(scratch + 3800000);  // 524288 bf16 (ends < 4.1M f32)

    // persistent across disto_k: keep in d_ws (1.54 MB)
    float* latentf = (float*)d_ws;      // 131072
    float* U       = latentf + 131072;  // 131072
    float* Vv      = U + 131072;        // 131072
    float* alphaf  = Vv + 131072;       // 512

    convw_k<<<1536, 256, 0, stream>>>(Wqkv, Wo, W1, W2, wb);
    embed_k<<<512, 256, 0, stream>>>(tokens, emb, x, xb);

    for (int l = 0; l < 4; ++l) {
        // qkv = xb . Wqkvb^T + bqkv  (f32 out, consumed by attn)
        gemm_bf<0, 0><<<dim3(12, 8), 256, 0, stream>>>(xb, wb, bqkv, qkv, nullptr,
                                                       768, 256, 256, 256,
                                                       (size_t)l * 196608, (size_t)l * 768);
        attn_k<<<dim3(128, 8), 256, 0, stream>>>(qkv, ob);
        // y = ob . Wob^T + bo (f32 out for residual+LN)
        gemm_bf<0, 0><<<dim3(4, 8), 256, 0, stream>>>(ob, wb, bo, y, nullptr,
                                                      256, 256, 256, 256,
                                                      786432 + (size_t)l * 65536, (size_t)l * 256);
        ln_res_k<<<512, 256, 0, stream>>>(x, y, ln1_g, ln1_b, (size_t)l * 256, xb);
        // ffhb = relu(xb . W1b^T + b1) (bf16 out)
        gemm_bf<1, 1><<<dim3(16, 8), 256, 0, stream>>>(xb, wb, b1, nullptr, ffhb,
                                                       1024, 256, 256, 256,
                                                       1048576 + (size_t)l * 262144, (size_t)l * 1024);
        // y = ffhb . W2b^T + b2 (f32 out)
        gemm_bf<0, 0><<<dim3(4, 8), 256, 0, stream>>>(ffhb, wb, b2, y, nullptr,
                                                      256, 1024, 1024, 1024,
                                                      2097152 + (size_t)l * 262144, (size_t)l * 256);
        ln_res_k<<<512, 256, 0, stream>>>(x, y, ln2_g, ln2_b, (size_t)l * 256, xb);
    }

    // alpha head (f32)
    gemm32<2><<<dim3(4, 16), 256, 0, stream>>>(x, aW1, ab1, t1,
                                               512, 256, 256, 256, 0, 0, 0);
    alpha_k<<<128, 256, 0, stream>>>(t1, aW2, ab2, alphaf, out_alpha);

    // CSOC kernel attention -> latent
    csock_k<<<512, 256, 0, stream>>>(x, alphaf, latentf, out_latent);

    // contact head (f32)
    gemm32<0><<<dim3(4, 16), 256, 0, stream>>>(latentf, cW, cb, hbuf,
                                               512, 256, 256, 256, 0, 0, 0);
    contact_k<<<512, 256, 0, stream>>>(hbuf, out_contact);

    // distogram first linear (separable, f32)
    gemm32<0><<<dim3(4, 16), 256, 0, stream>>>(latentf, dW1, db1, U,
                                               512, 256, 256, 512, 0, 0, 0);
    gemm32<0><<<dim3(4, 16), 256, 0, stream>>>(latentf, dW1, nullptr, Vv,
                                               512, 256, 256, 512, 256, 0, 0);

    // torsion head (f32; uses t1 scratch -> before disto_k)
    gemm32<2><<<dim3(4, 16), 256, 0, stream>>>(latentf, tW1, tb1, t1,
                                               512, 256, 256, 256, 0, 0, 0);
    torsion_k<<<128, 256, 0, stream>>>(t1, tW2, tb2, out_phi, out_psi);

    // diffusion coordinate init
    diff_k<<<6, 256, 0, stream>>>(latentf, pW, pb, noise, out_c);

    // distogram LAST: overwrites the scratch region with the real output
    disto_k<<<512, 256, 0, stream>>>(U, Vv, dW2, db2, out_disto);
}

// Round 11
// 509.138 us; speedup vs baseline: 2.6646x; 1.0415x over previous
//
#include <hip/hip_runtime.h>
#include <hip/hip_bf16.h>

typedef __attribute__((ext_vector_type(8))) short bf16x8;
typedef __attribute__((ext_vector_type(4))) float f32x4;
typedef unsigned short ushort;

// bf16 element offsets inside the converted-weight buffer wb
#define OFF_QKV 0
#define OFF_WO  786432
#define OFF_W1  1048576
#define OFF_W2  2097152
#define OFF_AW1 3145728
#define OFF_CW  3211264
#define OFF_DW1 3276800
#define OFF_TW1 3407872
#define WB_TOTAL 3473408

__device__ inline float gelu_f(float x) {
    return 0.5f * x * (1.0f + erff(x * 0.70710678118654752f));
}

__device__ inline ushort f2bfu(float x) {
    __hip_bfloat16 b = __float2bfloat16(x);
    return *reinterpret_cast<ushort*>(&b);
}

__device__ inline uint4 pack_bf8(float4 a, float4 b) {
    uint4 p;
    p.x = f2bfu(a.x) | ((unsigned)f2bfu(a.y) << 16);
    p.y = f2bfu(a.z) | ((unsigned)f2bfu(a.w) << 16);
    p.z = f2bfu(b.x) | ((unsigned)f2bfu(b.y) << 16);
    p.w = f2bfu(b.z) | ((unsigned)f2bfu(b.w) << 16);
    return p;
}

__device__ inline float wave_sum(float v) {
#pragma unroll
    for (int o = 32; o > 0; o >>= 1) v += __shfl_xor(v, o);
    return v;
}
__device__ inline float wave_max(float v) {
#pragma unroll
    for (int o = 32; o > 0; o >>= 1) v = fmaxf(v, __shfl_xor(v, o));
    return v;
}

// ---------------- weight conversion: all reused weights -> bf16, once ----------------
__global__ void convw_k(const float* __restrict__ Wqkv, const float* __restrict__ Wo,
                        const float* __restrict__ W1, const float* __restrict__ W2,
                        const float* __restrict__ aW1, const float* __restrict__ cW,
                        const float* __restrict__ dW1, const float* __restrict__ tW1,
                        ushort* __restrict__ dst) {
    size_t i = ((size_t)blockIdx.x * 256 + threadIdx.x) * 8;
    if (i >= WB_TOTAL) return;
    const float* src;
    size_t off;
    if (i < OFF_WO)        { src = Wqkv; off = i; }
    else if (i < OFF_W1)   { src = Wo;   off = i - OFF_WO; }
    else if (i < OFF_W2)   { src = W1;   off = i - OFF_W1; }
    else if (i < OFF_AW1)  { src = W2;   off = i - OFF_W2; }
    else if (i < OFF_CW)   { src = aW1;  off = i - OFF_AW1; }
    else if (i < OFF_DW1)  { src = cW;   off = i - OFF_CW; }
    else if (i < OFF_TW1)  { src = dW1;  off = i - OFF_DW1; }
    else                   { src = tW1;  off = i - OFF_TW1; }
    float4 f0 = *(const float4*)&src[off];
    float4 f1 = *(const float4*)&src[off + 4];
    *(uint4*)&dst[i] = pack_bf8(f0, f1);
}

// ---------------- embedding + positional encoding ----------------
__global__ void embed_k(const int* __restrict__ tokens, const float* __restrict__ emb,
                        float* __restrict__ x, ushort* __restrict__ xb) {
    int n = blockIdx.x, t = threadIdx.x;
    float e = emb[(size_t)tokens[n] * 256 + t];
    int k = t >> 1;
    float div = expf((float)(2 * k) * (-9.210340371976184f / 256.0f));
    float arg = (float)n * div;
    float v = e + ((t & 1) ? cosf(arg) : sinf(arg));
    x[(size_t)n * 256 + t] = v;
    xb[(size_t)n * 256 + t] = f2bfu(v);
}

// ---------------- MFMA GEMM, bf16 in / {f32 or bf16} out ----------------
// 64x64 tile, 4 waves, K-step 32, double-buffered LDS; staging is a pure
// uint4 copy. ACT: 0 none, 1 relu, 2 gelu.
template <int ACT, int OBF>
__global__ __launch_bounds__(256) void gemm_bf(const ushort* __restrict__ A,
                                               const ushort* __restrict__ Wb,
                                               const float* __restrict__ bias,
                                               float* __restrict__ C,
                                               ushort* __restrict__ Cb,
                                               int Nn, int K, int lda, int ldw, int koff,
                                               size_t woff, size_t boff) {
    __shared__ ushort Al[2][2048];
    __shared__ ushort Wl[2][2048];
    const int t = threadIdx.x;
    const int bm = blockIdx.y * 64, bn = blockIdx.x * 64;
    const int lane = t & 63, wv = t >> 6;
    const int lo = lane & 15, hi = lane >> 4;

    const ushort* aptr = A + (size_t)(bm + lane) * lda + wv * 8;
    const ushort* wptr = Wb + woff + (size_t)(bn + lane) * ldw + koff + wv * 8;

    f32x4 acc0 = {0.f, 0.f, 0.f, 0.f}, acc1 = acc0, acc2 = acc0, acc3 = acc0;
    uint4 a = *(const uint4*)aptr;
    uint4 w = *(const uint4*)wptr;
    const int nsteps = K >> 5;
    for (int s = 0; s < nsteps; ++s) {
        const int buf = s & 1;
        *(uint4*)&Al[buf][t * 8] = a;
        *(uint4*)&Wl[buf][t * 8] = w;
        __syncthreads();
        if (s + 1 < nsteps) {
            a = *(const uint4*)(aptr + (s + 1) * 32);
            w = *(const uint4*)(wptr + (s + 1) * 32);
        }
        bf16x8 af = *(bf16x8*)&Al[buf][(hi * 64 + wv * 16 + lo) * 8];
        bf16x8 b0 = *(bf16x8*)&Wl[buf][(hi * 64 + 0 + lo) * 8];
        bf16x8 b1 = *(bf16x8*)&Wl[buf][(hi * 64 + 16 + lo) * 8];
        bf16x8 b2 = *(bf16x8*)&Wl[buf][(hi * 64 + 32 + lo) * 8];
        bf16x8 b3 = *(bf16x8*)&Wl[buf][(hi * 64 + 48 + lo) * 8];
        acc0 = __builtin_amdgcn_mfma_f32_16x16x32_bf16(af, b0, acc0, 0, 0, 0);
        acc1 = __builtin_amdgcn_mfma_f32_16x16x32_bf16(af, b1, acc1, 0, 0, 0);
        acc2 = __builtin_amdgcn_mfma_f32_16x16x32_bf16(af, b2, acc2, 0, 0, 0);
        acc3 = __builtin_amdgcn_mfma_f32_16x16x32_bf16(af, b3, acc3, 0, 0, 0);
    }

    float bv0 = bias ? bias[boff + bn + 0 + lo] : 0.0f;
    float bv1 = bias ? bias[boff + bn + 16 + lo] : 0.0f;
    float bv2 = bias ? bias[boff + bn + 32 + lo] : 0.0f;
    float bv3 = bias ? bias[boff + bn + 48 + lo] : 0.0f;
#pragma unroll
    for (int r = 0; r < 4; ++r) {
        size_t rw = (size_t)(bm + wv * 16 + hi * 4 + r) * Nn + bn;
        float v0 = acc0[r] + bv0, v1 = acc1[r] + bv1, v2 = acc2[r] + bv2, v3 = acc3[r] + bv3;
        if (ACT == 1) {
            v0 = fmaxf(v0, 0.f); v1 = fmaxf(v1, 0.f); v2 = fmaxf(v2, 0.f); v3 = fmaxf(v3, 0.f);
        }
        if (ACT == 2) {
            v0 = gelu_f(v0); v1 = gelu_f(v1); v2 = gelu_f(v2); v3 = gelu_f(v3);
        }
        if (OBF) {
            Cb[rw + 0 + lo] = f2bfu(v0);
            Cb[rw + 16 + lo] = f2bfu(v1);
            Cb[rw + 32 + lo] = f2bfu(v2);
            Cb[rw + 48 + lo] = f2bfu(v3);
        } else {
            C[rw + 0 + lo] = v0;
            C[rw + 16 + lo] = v1;
            C[rw + 32 + lo] = v2;
            C[rw + 48 + lo] = v3;
        }
    }
}

// ---------------- attention: wave per (head, 1 query-group of 4), ILP-8 PV ----------------
__global__ __launch_bounds__(256) void attn_k(const float* __restrict__ qkv,
                                              ushort* __restrict__ ob) {
    __shared__ float sc[4][512];
    int t = threadIdx.x;
    int w = t >> 6, lane = t & 63;
    int q = blockIdx.x * 4 + w;
    int h = blockIdx.y;
    const float* qptr = qkv + (size_t)q * 768 + h * 32;
    const float* kbase = qkv + 256 + h * 32;
    const float* vbase = qkv + 512 + h * 32;
    float qv[32];
#pragma unroll
    for (int d = 0; d < 32; d += 4) {
        float4 f = *(const float4*)(qptr + d);
        qv[d] = f.x; qv[d + 1] = f.y; qv[d + 2] = f.z; qv[d + 3] = f.w;
    }
    float mx = -1e30f;
    for (int k = lane; k < 512; k += 64) {
        const float* kp = kbase + (size_t)k * 768;
        float s = 0.0f;
#pragma unroll
        for (int d = 0; d < 32; d += 4) {
            float4 f = *(const float4*)(kp + d);
            s = fmaf(qv[d], f.x, s); s = fmaf(qv[d + 1], f.y, s);
            s = fmaf(qv[d + 2], f.z, s); s = fmaf(qv[d + 3], f.w, s);
        }
        s *= 0.17677669529663687f;  // 1/sqrt(32)
        sc[w][k] = s;
        mx = fmaxf(mx, s);
    }
    mx = wave_max(mx);
    float sum = 0.0f;
    for (int k = lane; k < 512; k += 64) {
        float e = expf(sc[w][k] - mx);
        sc[w][k] = e;
        sum += e;
    }
    sum = wave_sum(sum);
    float inv = 1.0f / sum;
    __syncthreads();
    int d = lane & 31, half = lane >> 5;
    const float* vp = vbase + d;
    const int kb = half * 256;
    float a0 = 0.f, a1 = 0.f, a2 = 0.f, a3 = 0.f;
    float a4 = 0.f, a5 = 0.f, a6 = 0.f, a7 = 0.f;
    for (int k = kb; k < kb + 256; k += 8) {
        float4 p0 = *(const float4*)&sc[w][k];       // wave-uniform -> LDS broadcast
        float4 p1 = *(const float4*)&sc[w][k + 4];
        a0 = fmaf(p0.x, vp[(size_t)(k + 0) * 768], a0);
        a1 = fmaf(p0.y, vp[(size_t)(k + 1) * 768], a1);
        a2 = fmaf(p0.z, vp[(size_t)(k + 2) * 768], a2);
        a3 = fmaf(p0.w, vp[(size_t)(k + 3) * 768], a3);
        a4 = fmaf(p1.x, vp[(size_t)(k + 4) * 768], a4);
        a5 = fmaf(p1.y, vp[(size_t)(k + 5) * 768], a5);
        a6 = fmaf(p1.z, vp[(size_t)(k + 6) * 768], a6);
        a7 = fmaf(p1.w, vp[(size_t)(k + 7) * 768], a7);
    }
    float accv = ((a0 + a1) + (a2 + a3)) + ((a4 + a5) + (a6 + a7));
    accv += __shfl_down(accv, 32);
    if (lane < 32) ob[(size_t)q * 256 + h * 32 + d] = f2bfu(accv * inv);
}

// ---------------- residual + LayerNorm (f32 + bf16 copy) ----------------
__global__ void ln_res_k(float* __restrict__ x, const float* __restrict__ y,
                         const float* __restrict__ g, const float* __restrict__ b,
                         size_t goff, ushort* __restrict__ xb) {
    int row = blockIdx.x, t = threadIdx.x;
    __shared__ float red[8];
    float v = x[row * 256 + t] + y[row * 256 + t];
    float s = wave_sum(v);
    if ((t & 63) == 0) red[t >> 6] = s;
    __syncthreads();
    float mean = (red[0] + red[1] + red[2] + red[3]) * (1.0f / 256.0f);
    float d = v - mean;
    float s2 = wave_sum(d * d);
    if ((t & 63) == 0) red[4 + (t >> 6)] = s2;
    __syncthreads();
    float var = (red[4] + red[5] + red[6] + red[7]) * (1.0f / 256.0f);
    float res = d * rsqrtf(var + 1e-5f) * g[goff + t] + b[goff + t];
    x[row * 256 + t] = res;
    xb[row * 256 + t] = f2bfu(res);
}

// ---------------- alpha head ----------------
__global__ void alpha_k(const float* __restrict__ t1, const float* __restrict__ aW2,
                        const float* __restrict__ ab2, float* __restrict__ alphaf,
                        float* __restrict__ out_alpha) {
    int t = threadIdx.x, w = t >> 6, lane = t & 63;
    int n = blockIdx.x * 4 + w;
    const float* r = t1 + (size_t)n * 256;
    float s = 0.0f;
    for (int d = lane; d < 256; d += 64) s = fmaf(r[d], aW2[d], s);
    s = wave_sum(s);
    if (lane == 0) {
        float z = s + ab2[0];
        float a = 1.0f / (1.0f + expf(-z));
        float al = 1.2f + 2.3f * a;
        alphaf[n] = al;
        out_alpha[n] = al;
    }
}

// ---------------- CSOC kernel attention ----------------
__global__ void csock_k(const float* __restrict__ x, const float* __restrict__ alphaf,
                        float* __restrict__ latent, float* __restrict__ out_latent,
                        ushort* __restrict__ latentb) {
    int i = blockIdx.x, t = threadIdx.x;
    __shared__ float wgt[512];
    __shared__ float red[4];
    float ai = alphaf[i];
    float lsum = 0.0f;
    for (int j = t; j < 512; j += 256) {
        float r = fabsf((float)(i - j)) + 1e-4f;
        float ap = 0.5f * (ai + alphaf[j]);
        float wv = powf(r, -ap) * expf(-r * 0.1f);
        wgt[j] = wv;
        lsum += wv;
    }
    float s = wave_sum(lsum);
    if ((t & 63) == 0) red[t >> 6] = s;
    __syncthreads();
    float S = red[0] + red[1] + red[2] + red[3] + 1e-8f;
    float acc = 0.0f;
    for (int j = 0; j < 512; ++j) acc = fmaf(wgt[j], x[(size_t)j * 256 + t], acc);
    float res = acc / S;
    latent[(size_t)i * 256 + t] = res;
    out_latent[(size_t)i * 256 + t] = res;
    latentb[(size_t)i * 256 + t] = f2bfu(res);
}

// ---------------- contact head ----------------
__global__ void contact_k(const float* __restrict__ h, float* __restrict__ out) {
    int i = blockIdx.x, t = threadIdx.x;
    __shared__ float hi[256];
    hi[t] = h[(size_t)i * 256 + t];
    __syncthreads();
    for (int j = t; j < 512; j += 256) {
        const float* hj = h + (size_t)j * 256;
        float s = 0.0f;
#pragma unroll 4
        for (int d = 0; d < 256; d += 4) {
            float4 a = *(const float4*)&hi[d];
            float4 b = *(const float4*)&hj[d];
            s = fmaf(a.x, b.x, s); s = fmaf(a.y, b.y, s);
            s = fmaf(a.z, b.z, s); s = fmaf(a.w, b.w, s);
        }
        out[(size_t)i * 512 + j] = 1.0f / (1.0f + expf(-s));
    }
}

// ---------------- distogram (bf16 MFMA) ----------------
__global__ __launch_bounds__(256) void disto_k(const float* __restrict__ U,
                                               const float* __restrict__ V,
                                               const float* __restrict__ dW2,
                                               const float* __restrict__ db2,
                                               float* __restrict__ out) {
    __shared__ short hsl[32 * 64 * 8];
    __shared__ short w2l[32 * 64 * 8];
    const int t = threadIdx.x;
    const int i = blockIdx.x;
    const int row = t >> 2;
    const int dq = t & 3;

#pragma unroll
    for (int c = 0; c < 8; ++c) {
        int dblk = dq * 8 + c;
        int d0 = dblk * 8;
        float4 w0 = *(const float4*)&dW2[(size_t)row * 256 + d0];
        float4 w1 = *(const float4*)&dW2[(size_t)row * 256 + d0 + 4];
        *(uint4*)&w2l[(dblk * 64 + row) * 8] = pack_bf8(w0, w1);
    }

    const int wv = t >> 6, lane = t & 63;
    const int lo = lane & 15, hi = lane >> 4;
    const int jw = wv * 16;
    float dbv[4];
#pragma unroll
    for (int nt = 0; nt < 4; ++nt) dbv[nt] = db2[nt * 16 + lo];

    for (int p = 0; p < 8; ++p) {
        const int j0 = p * 64;
#pragma unroll
        for (int c = 0; c < 8; ++c) {
            int dblk = dq * 8 + c;
            int d0 = dblk * 8;
            float4 u0 = *(const float4*)&U[(size_t)i * 256 + d0];
            float4 u1 = *(const float4*)&U[(size_t)i * 256 + d0 + 4];
            float4 v0 = *(const float4*)&V[(size_t)(j0 + row) * 256 + d0];
            float4 v1 = *(const float4*)&V[(size_t)(j0 + row) * 256 + d0 + 4];
            float4 h0, h1;
            h0.x = gelu_f(u0.x + v0.x); h0.y = gelu_f(u0.y + v0.y);
            h0.z = gelu_f(u0.z + v0.z); h0.w = gelu_f(u0.w + v0.w);
            h1.x = gelu_f(u1.x + v1.x); h1.y = gelu_f(u1.y + v1.y);
            h1.z = gelu_f(u1.z + v1.z); h1.w = gelu_f(u1.w + v1.w);
            *(uint4*)&hsl[(dblk * 64 + row) * 8] = pack_bf8(h0, h1);
        }
        __syncthreads();

        f32x4 acc0 = {0.f, 0.f, 0.f, 0.f}, acc1 = acc0, acc2 = acc0, acc3 = acc0;
#pragma unroll
        for (int kk = 0; kk < 8; ++kk) {
            int db = kk * 4 + hi;
            bf16x8 a = *(bf16x8*)&hsl[(db * 64 + jw + lo) * 8];
            bf16x8 b0 = *(bf16x8*)&w2l[(db * 64 + 0 + lo) * 8];
            bf16x8 b1 = *(bf16x8*)&w2l[(db * 64 + 16 + lo) * 8];
            bf16x8 b2 = *(bf16x8*)&w2l[(db * 64 + 32 + lo) * 8];
            bf16x8 b3 = *(bf16x8*)&w2l[(db * 64 + 48 + lo) * 8];
            acc0 = __builtin_amdgcn_mfma_f32_16x16x32_bf16(a, b0, acc0, 0, 0, 0);
            acc1 = __builtin_amdgcn_mfma_f32_16x16x32_bf16(a, b1, acc1, 0, 0, 0);
            acc2 = __builtin_amdgcn_mfma_f32_16x16x32_bf16(a, b2, acc2, 0, 0, 0);
            acc3 = __builtin_amdgcn_mfma_f32_16x16x32_bf16(a, b3, acc3, 0, 0, 0);
        }
#pragma unroll
        for (int r = 0; r < 4; ++r) {
            size_t jg = (size_t)i * 512 + j0 + jw + hi * 4 + r;
            out[jg * 64 + 0 + lo] = acc0[r] + dbv[0];
            out[jg * 64 + 16 + lo] = acc1[r] + dbv[1];
            out[jg * 64 + 32 + lo] = acc2[r] + dbv[2];
            out[jg * 64 + 48 + lo] = acc3[r] + dbv[3];
        }
        __syncthreads();
    }
}

// ---------------- torsion head ----------------
__global__ void torsion_k(const float* __restrict__ t1, const float* __restrict__ tW2,
                          const float* __restrict__ tb2, float* __restrict__ phi,
                          float* __restrict__ psi) {
    int t = threadIdx.x, w = t >> 6, lane = t & 63;
    int n = blockIdx.x * 4 + w;
    const float* r = t1 + (size_t)n * 256;
    float s0 = 0.0f, s1 = 0.0f;
    for (int d = lane; d < 256; d += 64) {
        float v = r[d];
        s0 = fmaf(v, tW2[d], s0);
        s1 = fmaf(v, tW2[256 + d], s1);
    }
    s0 = wave_sum(s0);
    s1 = wave_sum(s1);
    if (lane == 0) {
        phi[n] = tanhf(s0 + tb2[0]) * 3.14159265358979323846f;
        psi[n] = tanhf(s1 + tb2[1]) * 3.14159265358979323846f;
    }
}

// ---------------- diffusion coordinate init ----------------
__global__ void diff_k(const float* __restrict__ latent, const float* __restrict__ pW,
                       const float* __restrict__ pb, const float* __restrict__ noise,
                       float* __restrict__ outc) {
    int idx = blockIdx.x * 256 + threadIdx.x;
    if (idx >= 512 * 3) return;
    int n = idx / 3, a = idx % 3;
    const float* r = latent + (size_t)n * 256;
    float s = pb[a];
    for (int d = 0; d < 256; ++d) s = fmaf(r[d], pW[(size_t)a * 256 + d], s);
    float c = noise[idx];
#pragma unroll
    for (int st = 9; st >= 0; --st) {
        float at = (float)(st + 1) * 0.1f;
        c = at * c + (1.0f - at) * s;
    }
    outc[idx] = c;
}

extern "C" void kernel_launch(void* const* d_in, const int* in_sizes, int n_in,
                              void* d_out, int out_size, void* d_ws, size_t ws_size,
                              hipStream_t stream) {
    const int* tokens  = (const int*)d_in[0];
    const float* noise = (const float*)d_in[1];
    const float* emb   = (const float*)d_in[2];
    const float* Wqkv  = (const float*)d_in[3];
    const float* bqkv  = (const float*)d_in[4];
    const float* Wo    = (const float*)d_in[5];
    const float* bo    = (const float*)d_in[6];
    const float* ln1_g = (const float*)d_in[7];
    const float* ln1_b = (const float*)d_in[8];
    const float* W1    = (const float*)d_in[9];
    const float* b1    = (const float*)d_in[10];
    const float* W2    = (const float*)d_in[11];
    const float* b2    = (const float*)d_in[12];
    const float* ln2_g = (const float*)d_in[13];
    const float* ln2_b = (const float*)d_in[14];
    const float* aW1   = (const float*)d_in[15];
    const float* ab1   = (const float*)d_in[16];
    const float* aW2   = (const float*)d_in[17];
    const float* ab2   = (const float*)d_in[18];
    const float* cW    = (const float*)d_in[19];
    const float* cb    = (const float*)d_in[20];
    const float* dW1   = (const float*)d_in[21];
    const float* db1   = (const float*)d_in[22];
    const float* dW2   = (const float*)d_in[23];
    const float* db2   = (const float*)d_in[24];
    const float* tW1   = (const float*)d_in[25];
    const float* tb1   = (const float*)d_in[26];
    const float* tW2   = (const float*)d_in[27];
    const float* tb2   = (const float*)d_in[28];
    const float* pW    = (const float*)d_in[29];
    const float* pb    = (const float*)d_in[30];

    // output layout (FLOAT32, concatenated in return order)
    float* out         = (float*)d_out;
    float* out_latent  = out;               // 131072
    float* out_alpha   = out + 131072;      // 512
    float* out_contact = out + 131584;      // 262144
    float* out_disto   = out + 393728;      // 16777216
    float* out_phi     = out + 17170944;    // 512
    float* out_psi     = out + 17171456;    // 512
    float* out_c       = out + 17171968;    // 1536

    // transient scratch inside out_disto (67 MB as f32); disto_k runs LAST and
    // reads only U/V (d_ws) + weights while overwriting this region.
    float* scratch = out_disto;
    float* x    = scratch;             // 131072 f32
    float* qkv  = scratch + 131072;    // 393216 f32
    float* y    = scratch + 1179648;   // 131072 f32
    float* hbuf = scratch + 1310720;   // 131072 f32
    float* t1   = scratch + 1441792;   // 131072 f32
    ushort* wb      = (ushort*)(scratch + 2000000);  // 3473408 bf16 -> 1736704 f32
    ushort* xb      = (ushort*)(scratch + 3740000);  // 131072 bf16
    ushort* ob      = (ushort*)(scratch + 3810000);  // 131072 bf16
    ushort* ffhb    = (ushort*)(scratch + 3880000);  // 524288 bf16
    ushort* latentb = (ushort*)(scratch + 4150000);  // 131072 bf16 (ends < 4.3M f32)

    // persistent across disto_k: keep in d_ws (1.54 MB)
    float* latentf = (float*)d_ws;      // 131072
    float* U       = latentf + 131072;  // 131072
    float* Vv      = U + 131072;        // 131072
    float* alphaf  = Vv + 131072;       // 512

    convw_k<<<1696, 256, 0, stream>>>(Wqkv, Wo, W1, W2, aW1, cW, dW1, tW1, wb);
    embed_k<<<512, 256, 0, stream>>>(tokens, emb, x, xb);

    for (int l = 0; l < 4; ++l) {
        gemm_bf<0, 0><<<dim3(12, 8), 256, 0, stream>>>(xb, wb, bqkv, qkv, nullptr,
                                                       768, 256, 256, 256, 0,
                                                       OFF_QKV + (size_t)l * 196608, (size_t)l * 768);
        attn_k<<<dim3(128, 8), 256, 0, stream>>>(qkv, ob);
        gemm_bf<0, 0><<<dim3(4, 8), 256, 0, stream>>>(ob, wb, bo, y, nullptr,
                                                      256, 256, 256, 256, 0,
                                                      OFF_WO + (size_t)l * 65536, (size_t)l * 256);
        ln_res_k<<<512, 256, 0, stream>>>(x, y, ln1_g, ln1_b, (size_t)l * 256, xb);
        gemm_bf<1, 1><<<dim3(16, 8), 256, 0, stream>>>(xb, wb, b1, nullptr, ffhb,
                                                       1024, 256, 256, 256, 0,
                                                       OFF_W1 + (size_t)l * 262144, (size_t)l * 1024);
        gemm_bf<0, 0><<<dim3(4, 8), 256, 0, stream>>>(ffhb, wb, b2, y, nullptr,
                                                      256, 1024, 1024, 1024, 0,
                                                      OFF_W2 + (size_t)l * 262144, (size_t)l * 256);
        ln_res_k<<<512, 256, 0, stream>>>(x, y, ln2_g, ln2_b, (size_t)l * 256, xb);
    }

    // alpha head: t1 = gelu(x.aW1^T + ab1) via MFMA
    gemm_bf<2, 0><<<dim3(4, 8), 256, 0, stream>>>(xb, wb, ab1, t1, nullptr,
                                                  256, 256, 256, 256, 0, OFF_AW1, 0);
    alpha_k<<<128, 256, 0, stream>>>(t1, aW2, ab2, alphaf, out_alpha);

    // CSOC kernel attention -> latent (f32 + bf16)
    csock_k<<<512, 256, 0, stream>>>(x, alphaf, latentf, out_latent, latentb);

    // contact head
    gemm_bf<0, 0><<<dim3(4, 8), 256, 0, stream>>>(latentb, wb, cb, hbuf, nullptr,
                                                  256, 256, 256, 256, 0, OFF_CW, 0);
    contact_k<<<512, 256, 0, stream>>>(hbuf, out_contact);

    // distogram first linear (separable): U (koff=0, +db1), V (koff=256)
    gemm_bf<0, 0><<<dim3(4, 8), 256, 0, stream>>>(latentb, wb, db1, U, nullptr,
                                                  256, 256, 256, 512, 0, OFF_DW1, 0);
    gemm_bf<0, 0><<<dim3(4, 8), 256, 0, stream>>>(latentb, wb, nullptr, Vv, nullptr,
                                                  256, 256, 256, 512, 256, OFF_DW1, 0);

    // torsion head
    gemm_bf<2, 0><<<dim3(4, 8), 256, 0, stream>>>(latentb, wb, tb1, t1, nullptr,
                                                  256, 256, 256, 256, 0, OFF_TW1, 0);
    torsion_k<<<128, 256, 0, stream>>>(t1, tW2, tb2, out_phi, out_psi);

    // diffusion coordinate init
    diff_k<<<6, 256, 0, stream>>>(latentf, pW, pb, noise, out_c);

    // distogram LAST: overwrites the scratch region with the real output
    disto_k<<<512, 256, 0, stream>>>(U, Vv, dW2, db2, out_disto);
}